// Round 2
// baseline (1912.068 us; speedup 1.0000x reference)
//
#include <hip/hip_runtime.h>
#include <hip/hip_bf16.h>

#define S_LEN 2048
#define DIM   1024
#define NHEAD 16
#define HDIM  64

typedef __attribute__((ext_vector_type(8))) short bfrag;   // 8 bf16 = 4 VGPRs
typedef __attribute__((ext_vector_type(4))) float f32x4;   // MFMA C/D

__device__ __forceinline__ unsigned short f2bf(float x) {
  __hip_bfloat16 h = __float2bfloat16(x);
  return *reinterpret_cast<unsigned short*>(&h);
}

// flags[0]: 0 = inputs bf16, 1 = inputs fp32
// flags[1]: mask mode 0=u8, 1=i32, 2=f32, 3=bf16
__global__ void probe(const unsigned int* __restrict__ x,
                      const unsigned int* __restrict__ mask,
                      int* __restrict__ flags) {
  if (threadIdx.x != 0) return;
  int insane = 0;
  for (int i = 0; i < 512; ++i) {
    unsigned int w = x[i];
    unsigned int e = (w >> 7) & 0xFFu;          // exponent of LOW bf16 half
    bool sane = (e >= 90u && e <= 160u) || ((w & 0x7FFFu) == 0u);
    insane += sane ? 0 : 1;
  }
  flags[0] = (insane > 128) ? 1 : 0;

  bool all01 = true, allu8 = true, allf32 = true, allbf = true;
  for (int i = 0; i < 1024; ++i) {
    unsigned int w = mask[i];
    all01  &= (w <= 1u);
    allu8  &= ((w & 0xFEFEFEFEu) == 0u);
    allf32 &= (w == 0u || w == 0x3F800000u);
    unsigned int lo = w & 0xFFFFu, hi = w >> 16;
    allbf  &= (lo == 0u || lo == 0x3F80u) && (hi == 0u || hi == 0x3F80u);
  }
  flags[1] = all01 ? 1 : (allu8 ? 0 : (allf32 ? 2 : (allbf ? 3 : 0)));
}

template<bool F32>
__device__ __forceinline__ bfrag load8(const void* base, size_t idx) {
  if constexpr (F32) {
    const float* p = (const float*)base + idx;
    float4 u = *reinterpret_cast<const float4*>(p);
    float4 v = *reinterpret_cast<const float4*>(p + 4);
    bfrag r;
    r[0] = (short)f2bf(u.x); r[1] = (short)f2bf(u.y);
    r[2] = (short)f2bf(u.z); r[3] = (short)f2bf(u.w);
    r[4] = (short)f2bf(v.x); r[5] = (short)f2bf(v.y);
    r[6] = (short)f2bf(v.z); r[7] = (short)f2bf(v.w);
    return r;
  } else {
    return *reinterpret_cast<const bfrag*>((const unsigned short*)base + idx);
  }
}

__device__ __forceinline__ bool mask_at(const void* mk, int mode, size_t idx) {
  switch (mode) {
    case 0:  return ((const unsigned char*)mk)[idx]  != 0;
    case 1:  return ((const int*)mk)[idx]            != 0;
    case 2:  return ((const unsigned int*)mk)[idx]   != 0u;
    default: return ((const unsigned short*)mk)[idx] != 0;
  }
}

// C(MxN) = A(MxK) @ Bt(NxK)^T. Wave computes 16 rows x 64 cols.
template<bool AF32, bool BF32>
__device__ __forceinline__ void gemm_body(const void* __restrict__ A,
                                          const void* __restrict__ Bt,
                                          void* __restrict__ C,
                                          int M, int N, int K, bool outF32) {
  const int lane = threadIdx.x & 63;
  const int wave = threadIdx.x >> 6;
  const int r16  = lane & 15;
  const int quad = lane >> 4;
  const int m0 = (blockIdx.y * 4 + wave) * 16;
  const int n0 = blockIdx.x * 64;

  f32x4 acc[4] = {{0,0,0,0},{0,0,0,0},{0,0,0,0},{0,0,0,0}};
  const size_t aoff = (size_t)(m0 + r16) * K + quad * 8;
  const size_t boff = (size_t)(n0 + r16) * K + quad * 8;

  for (int k0 = 0; k0 < K; k0 += 32) {
    bfrag a = load8<AF32>(A, aoff + k0);
#pragma unroll
    for (int t = 0; t < 4; ++t) {
      bfrag b = load8<BF32>(Bt, boff + (size_t)t * 16 * K + k0);
      acc[t] = __builtin_amdgcn_mfma_f32_16x16x32_bf16(a, b, acc[t], 0, 0, 0);
    }
  }
#pragma unroll
  for (int t = 0; t < 4; ++t)
#pragma unroll
    for (int r = 0; r < 4; ++r) {
      const size_t ci = (size_t)(m0 + quad * 4 + r) * N + n0 + t * 16 + r16;
      if (outF32) ((float*)C)[ci] = acc[t][r];
      else        ((unsigned short*)C)[ci] = f2bf(acc[t][r]);
    }
}

__global__ __launch_bounds__(256) void gemm_bt(const void* __restrict__ A,
                                               const void* __restrict__ Bt,
                                               void* __restrict__ C,
                                               int M, int N, int K,
                                               const int* __restrict__ flags,
                                               int aFollows, int outFollows) {
  const int f = flags[0];
  const bool aF = (aFollows != 0) && (f != 0);
  const bool bF = (f != 0);
  const bool oF = (outFollows != 0) && (f != 0);
  if (bF) {
    if (aF) gemm_body<true,  true>(A, Bt, C, M, N, K, oF);
    else    gemm_body<false, true>(A, Bt, C, M, N, K, oF);
  } else    gemm_body<false, false>(A, Bt, C, M, N, K, oF);
}

// Flash attention: one wave per (b, h, 16 q-rows); 32 keys per step.
__global__ __launch_bounds__(64) void fattn(
    const unsigned short* __restrict__ xq,
    const unsigned short* __restrict__ xk,
    const unsigned short* __restrict__ xv,
    const void*           __restrict__ mk,
    const int*            __restrict__ flags,
    unsigned short*       __restrict__ xo)
{
  __shared__ unsigned short smemP[16 * 32];
  const int lane = threadIdx.x;
  const int r16  = lane & 15;
  const int quad = lane >> 4;
  const int q0 = blockIdx.x * 16;
  const int h  = blockIdx.y;
  const int b  = blockIdx.z;
  const int mmode = flags[1];

  const size_t base  = (size_t)b * S_LEN * DIM + (size_t)h * HDIM;
  const size_t mbase = (size_t)b * S_LEN * S_LEN;

  bfrag aq0 = *reinterpret_cast<const bfrag*>(xq + base + (size_t)(q0 + r16) * DIM + quad * 8);
  bfrag aq1 = *reinterpret_cast<const bfrag*>(xq + base + (size_t)(q0 + r16) * DIM + 32 + quad * 8);

  f32x4 o[4] = {{0,0,0,0},{0,0,0,0},{0,0,0,0},{0,0,0,0}};
  float m_r[4] = {-1e30f, -1e30f, -1e30f, -1e30f};
  float l_r[4] = {0.f, 0.f, 0.f, 0.f};

  for (int kb = 0; kb < S_LEN; kb += 32) {
    const unsigned short* k0p = xk + base + (size_t)(kb + r16) * DIM + quad * 8;
    const unsigned short* k1p = k0p + (size_t)16 * DIM;
    f32x4 s0 = {0,0,0,0}, s1 = {0,0,0,0};
    s0 = __builtin_amdgcn_mfma_f32_16x16x32_bf16(aq0, *reinterpret_cast<const bfrag*>(k0p),      s0, 0,0,0);
    s0 = __builtin_amdgcn_mfma_f32_16x16x32_bf16(aq1, *reinterpret_cast<const bfrag*>(k0p + 32), s0, 0,0,0);
    s1 = __builtin_amdgcn_mfma_f32_16x16x32_bf16(aq0, *reinterpret_cast<const bfrag*>(k1p),      s1, 0,0,0);
    s1 = __builtin_amdgcn_mfma_f32_16x16x32_bf16(aq1, *reinterpret_cast<const bfrag*>(k1p + 32), s1, 0,0,0);

    float l0[4], l1[4], tmax[4];
#pragma unroll
    for (int r = 0; r < 4; ++r) {
      const size_t mrow = mbase + (size_t)(q0 + quad * 4 + r) * S_LEN + kb;
      const bool k0m = mask_at(mk, mmode, mrow + r16);
      const bool k1m = mask_at(mk, mmode, mrow + 16 + r16);
      l0[r] = k0m ? s0[r] * 0.125f : -1e30f;
      l1[r] = k1m ? s1[r] * 0.125f : -1e30f;
      tmax[r] = fmaxf(l0[r], l1[r]);
    }
#pragma unroll
    for (int off = 1; off < 16; off <<= 1)
#pragma unroll
      for (int r = 0; r < 4; ++r)
        tmax[r] = fmaxf(tmax[r], __shfl_xor(tmax[r], off, 64));

    float p0[4], p1[4], rsum[4];
#pragma unroll
    for (int r = 0; r < 4; ++r) {
      const float mnew  = fmaxf(m_r[r], tmax[r]);
      const float alpha = __expf(m_r[r] - mnew);
      m_r[r] = mnew;
      p0[r] = (l0[r] <= -1e29f) ? 0.f : __expf(l0[r] - mnew);
      p1[r] = (l1[r] <= -1e29f) ? 0.f : __expf(l1[r] - mnew);
      rsum[r] = p0[r] + p1[r];
      l_r[r] *= alpha;
#pragma unroll
      for (int t = 0; t < 4; ++t) o[t][r] *= alpha;
    }
#pragma unroll
    for (int off = 1; off < 16; off <<= 1)
#pragma unroll
      for (int r = 0; r < 4; ++r)
        rsum[r] += __shfl_xor(rsum[r], off, 64);
#pragma unroll
    for (int r = 0; r < 4; ++r) l_r[r] += rsum[r];

#pragma unroll
    for (int r = 0; r < 4; ++r) {
      smemP[(quad * 4 + r) * 32 + r16]      = f2bf(p0[r]);
      smemP[(quad * 4 + r) * 32 + 16 + r16] = f2bf(p1[r]);
    }
    __syncthreads();
    bfrag apf = *reinterpret_cast<const bfrag*>(&smemP[r16 * 32 + quad * 8]);

    const unsigned short* vbase = xv + base + (size_t)(kb + quad * 8) * DIM + r16;
#pragma unroll
    for (int t = 0; t < 4; ++t) {
      bfrag bv;
#pragma unroll
      for (int j = 0; j < 8; ++j)
        bv[j] = (short)vbase[(size_t)j * DIM + t * 16];
      o[t] = __builtin_amdgcn_mfma_f32_16x16x32_bf16(apf, bv, o[t], 0, 0, 0);
    }
    __syncthreads();
  }
#pragma unroll
  for (int t = 0; t < 4; ++t)
#pragma unroll
    for (int r = 0; r < 4; ++r)
      xo[base + (size_t)(q0 + quad * 4 + r) * DIM + t * 16 + r16] = f2bf(o[t][r] / l_r[r]);
}

extern "C" void kernel_launch(void* const* d_in, const int* in_sizes, int n_in,
                              void* d_out, int out_size, void* d_ws, size_t ws_size,
                              hipStream_t stream)
{
  const void* x  = d_in[0];
  const void* mk = d_in[1];
  const void* wq = d_in[2];
  const void* wk = d_in[3];
  const void* wv = d_in[4];
  const void* wo = d_in[5];

  // ws layout: [flags 256B] [xq 16MiB] [xk 16MiB] [xv 16MiB] [xo 16MiB]
  int* flags = (int*)d_ws;
  unsigned short* xq = (unsigned short*)((char*)d_ws + 256);
  unsigned short* xk = xq + (size_t)8388608;
  unsigned short* xv = xk + (size_t)8388608;
  unsigned short* xo = xv + (size_t)8388608;

  probe<<<1, 64, 0, stream>>>((const unsigned int*)x, (const unsigned int*)mk, flags);

  dim3 ggrid(16, 128);  // N/64, M/64
  gemm_bt<<<ggrid, 256, 0, stream>>>(x, wq, xq, 8192, 1024, 1024, flags, 1, 0);
  gemm_bt<<<ggrid, 256, 0, stream>>>(x, wk, xk, 8192, 1024, 1024, flags, 1, 0);
  gemm_bt<<<ggrid, 256, 0, stream>>>(x, wv, xv, 8192, 1024, 1024, flags, 1, 0);

  fattn<<<dim3(128, NHEAD, 4), 64, 0, stream>>>(xq, xk, xv, mk, flags, xo);

  gemm_bt<<<ggrid, 256, 0, stream>>>(xo, wo, d_out, 8192, 1024, 1024, flags, 0, 1);
}

// Round 4
// 700.849 us; speedup vs baseline: 2.7282x; 2.7282x over previous
//
#include <hip/hip_runtime.h>
#include <hip/hip_bf16.h>

#define S_LEN 2048
#define DIM   1024
#define NHEAD 16
#define HDIM  64
#define NTOK  8192   // B*S

typedef __attribute__((ext_vector_type(8))) short bfrag;   // 8 bf16 = 4 VGPRs
typedef __attribute__((ext_vector_type(4))) float f32x4;   // MFMA C/D

#define MFMA(a,b,c) __builtin_amdgcn_mfma_f32_16x16x32_bf16((a),(b),(c),0,0,0)

__device__ __forceinline__ unsigned short f2bf(float x) {
  __hip_bfloat16 h = __float2bfloat16(x);
  return *reinterpret_cast<unsigned short*>(&h);
}

// async global->LDS, 16B per lane; LDS dest = wave-uniform base + lane*16
__device__ __forceinline__ void gll16(const unsigned short* g, unsigned short* l) {
  __builtin_amdgcn_global_load_lds(
      (const __attribute__((address_space(1))) unsigned int*)g,
      (__attribute__((address_space(3))) unsigned int*)l, 16, 0, 0);
}

// flags[0]: 0 = inputs bf16, 1 = inputs fp32
// flags[1]: mask mode 0=u8, 1=i32, 2=f32, 3=bf16
__global__ void probe(const unsigned int* __restrict__ x,
                      const unsigned int* __restrict__ mask,
                      int* __restrict__ flags) {
  if (threadIdx.x != 0) return;
  int insane = 0;
  for (int i = 0; i < 512; ++i) {
    unsigned int w = x[i];
    unsigned int e = (w >> 7) & 0xFFu;
    bool sane = (e >= 90u && e <= 160u) || ((w & 0x7FFFu) == 0u);
    insane += sane ? 0 : 1;
  }
  flags[0] = (insane > 128) ? 1 : 0;

  bool all01 = true, allu8 = true, allf32 = true, allbf = true;
  for (int i = 0; i < 1024; ++i) {
    unsigned int w = mask[i];
    all01  &= (w <= 1u);
    allu8  &= ((w & 0xFEFEFEFEu) == 0u);
    allf32 &= (w == 0u || w == 0x3F800000u);
    unsigned int lo = w & 0xFFFFu, hi = w >> 16;
    allbf  &= (lo == 0u || lo == 0x3F80u) && (hi == 0u || hi == 0x3F80u);
  }
  flags[1] = all01 ? 1 : (allu8 ? 0 : (allf32 ? 2 : (allbf ? 3 : 0)));
}

__device__ __forceinline__ bool mask_at(const void* mk, int mode, size_t idx) {
  switch (mode) {
    case 0:  return ((const unsigned char*)mk)[idx]  != 0;
    case 1:  return ((const int*)mk)[idx]            != 0;
    case 2:  return ((const unsigned int*)mk)[idx]   != 0u;
    default: return ((const unsigned short*)mk)[idx] != 0;
  }
}

// Convert fp32-or-bf16 source to bf16, 8 elems/thread.
__global__ __launch_bounds__(256) void cvt(const void* __restrict__ src,
                                           unsigned short* __restrict__ dst,
                                           int n8, const int* __restrict__ flags) {
  int i = blockIdx.x * 256 + threadIdx.x;
  if (i >= n8) return;
  if (flags[0]) {
    const float* p = (const float*)src + (size_t)i * 8;
    float4 a = *reinterpret_cast<const float4*>(p);
    float4 b = *reinterpret_cast<const float4*>(p + 4);
    bfrag r;
    r[0]=(short)f2bf(a.x); r[1]=(short)f2bf(a.y); r[2]=(short)f2bf(a.z); r[3]=(short)f2bf(a.w);
    r[4]=(short)f2bf(b.x); r[5]=(short)f2bf(b.y); r[6]=(short)f2bf(b.z); r[7]=(short)f2bf(b.w);
    *reinterpret_cast<bfrag*>(dst + (size_t)i * 8) = r;
  } else {
    *reinterpret_cast<bfrag*>(dst + (size_t)i * 8) =
        reinterpret_cast<const bfrag*>(src)[i];
  }
}

// Bit-pack mask (any mode) -> u64 per 64 keys via ballot.
__global__ __launch_bounds__(256) void bitmask(const void* __restrict__ mk,
                                               const int* __restrict__ flags,
                                               unsigned long long* __restrict__ mb) {
  size_t gid = (size_t)blockIdx.x * 256 + threadIdx.x;
  bool v = mask_at(mk, flags[1], gid);
  unsigned long long w = __ballot(v);
  if ((threadIdx.x & 63) == 0) mb[gid >> 6] = w;
}

// ---------------- m97-style GEMM: C(8192x1024) = A @ Bt^T, bf16 ----------------
// BM=BN=128, BK=32; 256 thr = 4 waves, wave -> 64x64 (4x4 MFMA 16x16x32).
__global__ __launch_bounds__(256) void gemm128(const unsigned short* __restrict__ A,
                                               const unsigned short* __restrict__ Bt,
                                               void* __restrict__ C,
                                               const int* __restrict__ flags,
                                               int aHsplit, int cMode) {
  __shared__ unsigned short As[128 * 32];
  __shared__ unsigned short Bs[128 * 32];
  const int t = threadIdx.x, lane = t & 63, wave = t >> 6;
  const int r16 = lane & 15, quad = lane >> 4;
  const int n0 = blockIdx.x * 128, m0 = blockIdx.y * 128;
  const int wm = (wave >> 1) * 64, wn = (wave & 1) * 64;
  const int arow = t >> 2, aseg = (t & 3) * 8;

  f32x4 acc[4][4];
#pragma unroll
  for (int i = 0; i < 4; ++i)
#pragma unroll
    for (int j = 0; j < 4; ++j) acc[i][j] = (f32x4){0.f, 0.f, 0.f, 0.f};

  for (int k0 = 0; k0 < 1024; k0 += 32) {
    __syncthreads();
#pragma unroll
    for (int rr = 0; rr < 2; ++rr) {
      const int m = m0 + rr * 64 + arow;
      const int k = k0 + aseg;
      const unsigned short* ga;
      if (aHsplit) ga = A + ((size_t)(((m >> 11) << 4) + (k >> 6)) * 2048 + (m & 2047)) * 64 + (k & 63);
      else         ga = A + (size_t)m * 1024 + k;
      gll16(ga, As + rr * 2048 + wave * 512);
      const unsigned short* gb = Bt + (size_t)(n0 + rr * 64 + arow) * 1024 + k0 + aseg;
      gll16(gb, Bs + rr * 2048 + wave * 512);
    }
    __syncthreads();

    bfrag af[4], bf[4];
#pragma unroll
    for (int i = 0; i < 4; ++i)
      af[i] = *reinterpret_cast<const bfrag*>(&As[(wm + i * 16 + r16) * 32 + quad * 8]);
#pragma unroll
    for (int j = 0; j < 4; ++j)
      bf[j] = *reinterpret_cast<const bfrag*>(&Bs[(wn + j * 16 + r16) * 32 + quad * 8]);
#pragma unroll
    for (int i = 0; i < 4; ++i)
#pragma unroll
      for (int j = 0; j < 4; ++j)
        acc[i][j] = MFMA(af[i], bf[j], acc[i][j]);
  }

  const int oF = (cMode == 2) ? flags[0] : 0;
#pragma unroll
  for (int i = 0; i < 4; ++i)
#pragma unroll
    for (int j = 0; j < 4; ++j)
#pragma unroll
      for (int r = 0; r < 4; ++r) {
        const int m = m0 + wm + i * 16 + quad * 4 + r;
        const int n = n0 + wn + j * 16 + r16;
        const float v = acc[i][j][r];
        if (cMode == 1) {
          const size_t idx = ((size_t)((m >> 11) * 16 + (n >> 6)) * 2048 + (m & 2047)) * 64 + (n & 63);
          ((unsigned short*)C)[idx] = f2bf(v);
        } else {
          const size_t idx = (size_t)m * 1024 + n;
          if (oF) ((float*)C)[idx] = v;
          else    ((unsigned short*)C)[idx] = f2bf(v);
        }
      }
}

// xvH [bh][s][64] -> xvT [bh][64][s], 64x64 tiles through LDS.
// FIXED: rr-loop covers all 64 rows (round-3 covered 32 -> uninit LDS -> NaN);
// LDS stride 80 elems (160 B) keeps 16-B ds_read_b128 aligned.
__global__ __launch_bounds__(256) void transposeV(const unsigned short* __restrict__ xvH,
                                                  unsigned short* __restrict__ xvT) {
  __shared__ unsigned short Ts[64 * 80];
  const int t = threadIdx.x;
  const int s0 = blockIdx.x * 64, bh = blockIdx.y;
  const int sr = t >> 3, seg = (t & 7) * 8;   // sr in [0,32)
#pragma unroll
  for (int rr = 0; rr < 2; ++rr) {
    const int s = rr * 32 + sr;
    bfrag v = *reinterpret_cast<const bfrag*>(xvH + ((size_t)bh * 2048 + s0 + s) * 64 + seg);
#pragma unroll
    for (int j = 0; j < 8; ++j) Ts[(seg + j) * 80 + s] = (unsigned short)v[j];
  }
  __syncthreads();
#pragma unroll
  for (int rr = 0; rr < 2; ++rr) {
    const int d = rr * 32 + sr;
    bfrag o = *reinterpret_cast<const bfrag*>(&Ts[d * 80 + seg]);
    *reinterpret_cast<bfrag*>(xvT + ((size_t)bh * 64 + d) * 2048 + s0 + seg) = o;
  }
}

// ---------------- fattn v3: 4 waves x 16 q-rows, 64 keys/step, LDS-staged ----------------
__global__ __launch_bounds__(256) void fattn(const unsigned short* __restrict__ qH,
                                             const unsigned short* __restrict__ kH,
                                             const unsigned short* __restrict__ vT,
                                             const unsigned long long* __restrict__ mb,
                                             unsigned short* __restrict__ oH) {
  __shared__ unsigned short Ks[64 * 64];
  __shared__ unsigned short Vs[64 * 64];
  __shared__ unsigned short Ps[4 * 16 * 64];
  const int t = threadIdx.x, lane = t & 63, wave = t >> 6;
  const int r16 = lane & 15, quad = lane >> 4;
  const int q0 = blockIdx.x * 64;
  const int h = blockIdx.y, b = blockIdx.z;
  const int bh = b * 16 + h;
  const int qw = q0 + wave * 16;
  const size_t hbase = (size_t)bh * 2048;

  bfrag aq0 = *reinterpret_cast<const bfrag*>(qH + (hbase + qw + r16) * 64 + quad * 8);
  bfrag aq1 = *reinterpret_cast<const bfrag*>(qH + (hbase + qw + r16) * 64 + 32 + quad * 8);

  f32x4 o[4];
#pragma unroll
  for (int i = 0; i < 4; ++i) o[i] = (f32x4){0.f, 0.f, 0.f, 0.f};
  float m_r[4] = {-1e30f, -1e30f, -1e30f, -1e30f};
  float l_r[4] = {0.f, 0.f, 0.f, 0.f};

  const int srow = t >> 3, sseg = (t & 7) * 8;

  for (int kb = 0; kb < S_LEN; kb += 64) {
    __syncthreads();
#pragma unroll
    for (int rr = 0; rr < 2; ++rr) {
      gll16(kH + (hbase + kb + rr * 32 + srow) * 64 + sseg, Ks + rr * 2048 + wave * 512);
      gll16(vT + ((size_t)bh * 64 + rr * 32 + srow) * 2048 + kb + sseg, Vs + rr * 2048 + wave * 512);
    }
    __syncthreads();

    f32x4 s[4];
#pragma unroll
    for (int t4 = 0; t4 < 4; ++t4) {
      f32x4 z = (f32x4){0.f, 0.f, 0.f, 0.f};
      bfrag k0f = *reinterpret_cast<const bfrag*>(&Ks[(t4 * 16 + r16) * 64 + quad * 8]);
      bfrag k1f = *reinterpret_cast<const bfrag*>(&Ks[(t4 * 16 + r16) * 64 + 32 + quad * 8]);
      z = MFMA(aq0, k0f, z);
      z = MFMA(aq1, k1f, z);
      s[t4] = z;
    }

    unsigned long long w[4];
#pragma unroll
    for (int r = 0; r < 4; ++r)
      w[r] = mb[((size_t)b * S_LEN + qw + quad * 4 + r) * 32 + (kb >> 6)];

    float p[4][4], tmax[4], rsum[4];
#pragma unroll
    for (int r = 0; r < 4; ++r) {
      float mx = -1e30f;
#pragma unroll
      for (int t4 = 0; t4 < 4; ++t4) {
        const bool keep = (w[r] >> (t4 * 16 + r16)) & 1ull;
        const float l = keep ? s[t4][r] * 0.125f : -1e30f;
        p[t4][r] = l;
        mx = fmaxf(mx, l);
      }
      tmax[r] = mx;
    }
#pragma unroll
    for (int off = 1; off < 16; off <<= 1)
#pragma unroll
      for (int r = 0; r < 4; ++r)
        tmax[r] = fmaxf(tmax[r], __shfl_xor(tmax[r], off, 64));

#pragma unroll
    for (int r = 0; r < 4; ++r) {
      const float mnew = fmaxf(m_r[r], tmax[r]);
      const float alpha = __expf(m_r[r] - mnew);
      m_r[r] = mnew;
      l_r[r] *= alpha;
      float rs = 0.f;
#pragma unroll
      for (int t4 = 0; t4 < 4; ++t4) {
        const float v = (p[t4][r] <= -1e29f) ? 0.f : __expf(p[t4][r] - mnew);
        p[t4][r] = v;
        rs += v;
      }
      rsum[r] = rs;
#pragma unroll
      for (int t4 = 0; t4 < 4; ++t4) o[t4][r] *= alpha;
    }
#pragma unroll
    for (int off = 1; off < 16; off <<= 1)
#pragma unroll
      for (int r = 0; r < 4; ++r)
        rsum[r] += __shfl_xor(rsum[r], off, 64);
#pragma unroll
    for (int r = 0; r < 4; ++r) l_r[r] += rsum[r];

#pragma unroll
    for (int r = 0; r < 4; ++r)
#pragma unroll
      for (int t4 = 0; t4 < 4; ++t4)
        Ps[wave * 1024 + (quad * 4 + r) * 64 + t4 * 16 + r16] = f2bf(p[t4][r]);
    __asm__ volatile("s_waitcnt lgkmcnt(0)" ::: "memory");

    bfrag pa0 = *reinterpret_cast<const bfrag*>(&Ps[wave * 1024 + r16 * 64 + quad * 8]);
    bfrag pa1 = *reinterpret_cast<const bfrag*>(&Ps[wave * 1024 + r16 * 64 + 32 + quad * 8]);
#pragma unroll
    for (int t4 = 0; t4 < 4; ++t4) {
      bfrag v0 = *reinterpret_cast<const bfrag*>(&Vs[(t4 * 16 + r16) * 64 + quad * 8]);
      bfrag v1 = *reinterpret_cast<const bfrag*>(&Vs[(t4 * 16 + r16) * 64 + 32 + quad * 8]);
      o[t4] = MFMA(pa0, v0, o[t4]);
      o[t4] = MFMA(pa1, v1, o[t4]);
    }
  }
#pragma unroll
  for (int t4 = 0; t4 < 4; ++t4)
#pragma unroll
    for (int r = 0; r < 4; ++r)
      oH[(hbase + qw + quad * 4 + r) * 64 + t4 * 16 + r16] = f2bf(o[t4][r] / l_r[r]);
}

// ======================= round-2 fallback (small ws) =======================
template<bool F32>
__device__ __forceinline__ bfrag load8(const void* base, size_t idx) {
  if constexpr (F32) {
    const float* p = (const float*)base + idx;
    float4 u = *reinterpret_cast<const float4*>(p);
    float4 v = *reinterpret_cast<const float4*>(p + 4);
    bfrag r;
    r[0]=(short)f2bf(u.x); r[1]=(short)f2bf(u.y); r[2]=(short)f2bf(u.z); r[3]=(short)f2bf(u.w);
    r[4]=(short)f2bf(v.x); r[5]=(short)f2bf(v.y); r[6]=(short)f2bf(v.z); r[7]=(short)f2bf(v.w);
    return r;
  } else {
    return *reinterpret_cast<const bfrag*>((const unsigned short*)base + idx);
  }
}

template<bool AF32, bool BF32>
__device__ __forceinline__ void gemm_body(const void* __restrict__ A, const void* __restrict__ Bt,
                                          void* __restrict__ C, int N, int K, bool outF32) {
  const int lane = threadIdx.x & 63, wave = threadIdx.x >> 6;
  const int r16 = lane & 15, quad = lane >> 4;
  const int m0 = (blockIdx.y * 4 + wave) * 16, n0 = blockIdx.x * 64;
  f32x4 acc[4];
#pragma unroll
  for (int i = 0; i < 4; ++i) acc[i] = (f32x4){0.f,0.f,0.f,0.f};
  const size_t aoff = (size_t)(m0 + r16) * K + quad * 8;
  const size_t boff = (size_t)(n0 + r16) * K + quad * 8;
  for (int k0 = 0; k0 < K; k0 += 32) {
    bfrag a = load8<AF32>(A, aoff + k0);
#pragma unroll
    for (int tt = 0; tt < 4; ++tt) {
      bfrag bb = load8<BF32>(Bt, boff + (size_t)tt * 16 * K + k0);
      acc[tt] = MFMA(a, bb, acc[tt]);
    }
  }
#pragma unroll
  for (int tt = 0; tt < 4; ++tt)
#pragma unroll
    for (int r = 0; r < 4; ++r) {
      const size_t ci = (size_t)(m0 + quad * 4 + r) * N + n0 + tt * 16 + r16;
      if (outF32) ((float*)C)[ci] = acc[tt][r];
      else        ((unsigned short*)C)[ci] = f2bf(acc[tt][r]);
    }
}

__global__ __launch_bounds__(256) void gemm_bt(const void* A, const void* Bt, void* C,
                                               int N, int K, const int* flags,
                                               int aFollows, int outFollows) {
  const int f = flags[0];
  const bool aF = (aFollows != 0) && (f != 0);
  const bool oF = (outFollows != 0) && (f != 0);
  if (f) { if (aF) gemm_body<true, true>(A, Bt, C, N, K, oF);
           else    gemm_body<false, true>(A, Bt, C, N, K, oF); }
  else     gemm_body<false, false>(A, Bt, C, N, K, oF);
}

__global__ __launch_bounds__(64) void fattn_r2(const unsigned short* __restrict__ xq,
                                               const unsigned short* __restrict__ xk,
                                               const unsigned short* __restrict__ xv,
                                               const void* __restrict__ mk,
                                               const int* __restrict__ flags,
                                               unsigned short* __restrict__ xo) {
  __shared__ unsigned short smemP[16 * 32];
  const int lane = threadIdx.x, r16 = lane & 15, quad = lane >> 4;
  const int q0 = blockIdx.x * 16, h = blockIdx.y, b = blockIdx.z;
  const int mmode = flags[1];
  const size_t base = (size_t)b * S_LEN * DIM + (size_t)h * HDIM;
  const size_t mbase = (size_t)b * S_LEN * S_LEN;
  bfrag aq0 = *reinterpret_cast<const bfrag*>(xq + base + (size_t)(q0 + r16) * DIM + quad * 8);
  bfrag aq1 = *reinterpret_cast<const bfrag*>(xq + base + (size_t)(q0 + r16) * DIM + 32 + quad * 8);
  f32x4 o[4];
#pragma unroll
  for (int i = 0; i < 4; ++i) o[i] = (f32x4){0.f,0.f,0.f,0.f};
  float m_r[4] = {-1e30f,-1e30f,-1e30f,-1e30f}, l_r[4] = {0.f,0.f,0.f,0.f};
  for (int kb = 0; kb < S_LEN; kb += 32) {
    const unsigned short* k0p = xk + base + (size_t)(kb + r16) * DIM + quad * 8;
    const unsigned short* k1p = k0p + (size_t)16 * DIM;
    f32x4 s0 = (f32x4){0.f,0.f,0.f,0.f}, s1 = (f32x4){0.f,0.f,0.f,0.f};
    s0 = MFMA(aq0, *reinterpret_cast<const bfrag*>(k0p), s0);
    s0 = MFMA(aq1, *reinterpret_cast<const bfrag*>(k0p + 32), s0);
    s1 = MFMA(aq0, *reinterpret_cast<const bfrag*>(k1p), s1);
    s1 = MFMA(aq1, *reinterpret_cast<const bfrag*>(k1p + 32), s1);
    float l0[4], l1[4], tmax[4];
#pragma unroll
    for (int r = 0; r < 4; ++r) {
      const size_t mrow = mbase + (size_t)(q0 + quad * 4 + r) * S_LEN + kb;
      l0[r] = mask_at(mk, mmode, mrow + r16) ? s0[r] * 0.125f : -1e30f;
      l1[r] = mask_at(mk, mmode, mrow + 16 + r16) ? s1[r] * 0.125f : -1e30f;
      tmax[r] = fmaxf(l0[r], l1[r]);
    }
#pragma unroll
    for (int off = 1; off < 16; off <<= 1)
#pragma unroll
      for (int r = 0; r < 4; ++r) tmax[r] = fmaxf(tmax[r], __shfl_xor(tmax[r], off, 64));
    float p0[4], p1[4], rsum[4];
#pragma unroll
    for (int r = 0; r < 4; ++r) {
      const float mnew = fmaxf(m_r[r], tmax[r]);
      const float alpha = __expf(m_r[r] - mnew);
      m_r[r] = mnew;
      p0[r] = (l0[r] <= -1e29f) ? 0.f : __expf(l0[r] - mnew);
      p1[r] = (l1[r] <= -1e29f) ? 0.f : __expf(l1[r] - mnew);
      rsum[r] = p0[r] + p1[r];
      l_r[r] *= alpha;
#pragma unroll
      for (int tt = 0; tt < 4; ++tt) o[tt][r] *= alpha;
    }
#pragma unroll
    for (int off = 1; off < 16; off <<= 1)
#pragma unroll
      for (int r = 0; r < 4; ++r) rsum[r] += __shfl_xor(rsum[r], off, 64);
#pragma unroll
    for (int r = 0; r < 4; ++r) l_r[r] += rsum[r];
#pragma unroll
    for (int r = 0; r < 4; ++r) {
      smemP[(quad * 4 + r) * 32 + r16] = f2bf(p0[r]);
      smemP[(quad * 4 + r) * 32 + 16 + r16] = f2bf(p1[r]);
    }
    __syncthreads();
    bfrag apf = *reinterpret_cast<const bfrag*>(&smemP[r16 * 32 + quad * 8]);
    const unsigned short* vbase = xv + base + (size_t)(kb + quad * 8) * DIM + r16;
#pragma unroll
    for (int tt = 0; tt < 4; ++tt) {
      bfrag bv;
#pragma unroll
      for (int j = 0; j < 8; ++j) bv[j] = (short)vbase[(size_t)j * DIM + tt * 16];
      o[tt] = MFMA(apf, bv, o[tt]);
    }
    __syncthreads();
  }
#pragma unroll
  for (int tt = 0; tt < 4; ++tt)
#pragma unroll
    for (int r = 0; r < 4; ++r)
      xo[base + (size_t)(q0 + quad * 4 + r) * DIM + tt * 16 + r16] = f2bf(o[tt][r] / l_r[r]);
}

extern "C" void kernel_launch(void* const* d_in, const int* in_sizes, int n_in,
                              void* d_out, int out_size, void* d_ws, size_t ws_size,
                              hipStream_t stream) {
  const void* x  = d_in[0];
  const void* mk = d_in[1];
  const void* wq = d_in[2];
  const void* wk = d_in[3];
  const void* wv = d_in[4];
  const void* wo = d_in[5];

  const size_t MiB = 1048576;
  const size_t NEED = 4096 + 90 * MiB;

  if (ws_size >= NEED) {
    char* p = (char*)d_ws;
    int* flags = (int*)p;                       p += 4096;
    unsigned short* xb  = (unsigned short*)p;   p += 16 * MiB;
    unsigned short* wqb = (unsigned short*)p;   p += 2 * MiB;
    unsigned short* wkb = (unsigned short*)p;   p += 2 * MiB;
    unsigned short* wvb = (unsigned short*)p;   p += 2 * MiB;
    unsigned short* wob = (unsigned short*)p;   p += 2 * MiB;
    unsigned long long* mb = (unsigned long long*)p; p += 2 * MiB;
    unsigned short* xqH = (unsigned short*)p;   p += 16 * MiB;
    unsigned short* xkH = (unsigned short*)p;   p += 16 * MiB;
    unsigned short* xvH = (unsigned short*)p;   p += 16 * MiB;  // reused as xoH
    unsigned short* xvT = (unsigned short*)p;   p += 16 * MiB;
    unsigned short* xoH = xvH;  // xvH dead after transposeV

    probe<<<1, 64, 0, stream>>>((const unsigned int*)x, (const unsigned int*)mk, flags);
    cvt<<<4096, 256, 0, stream>>>(x,  xb,  1048576, flags);
    cvt<<<512,  256, 0, stream>>>(wq, wqb, 131072, flags);
    cvt<<<512,  256, 0, stream>>>(wk, wkb, 131072, flags);
    cvt<<<512,  256, 0, stream>>>(wv, wvb, 131072, flags);
    cvt<<<512,  256, 0, stream>>>(wo, wob, 131072, flags);
    bitmask<<<65536, 256, 0, stream>>>(mk, flags, mb);

    dim3 gg(8, 64);
    gemm128<<<gg, 256, 0, stream>>>(xb, wqb, xqH, flags, 0, 1);
    gemm128<<<gg, 256, 0, stream>>>(xb, wkb, xkH, flags, 0, 1);
    gemm128<<<gg, 256, 0, stream>>>(xb, wvb, xvH, flags, 0, 1);
    transposeV<<<dim3(32, 64), 256, 0, stream>>>(xvH, xvT);
    fattn<<<dim3(32, NHEAD, 4), 256, 0, stream>>>(xqH, xkH, xvT, mb, xoH);
    gemm128<<<gg, 256, 0, stream>>>(xoH, wob, d_out, flags, 1, 2);
  } else {
    // round-2 fallback
    int* flags = (int*)d_ws;
    unsigned short* xq = (unsigned short*)((char*)d_ws + 256);
    unsigned short* xk = xq + (size_t)8388608;
    unsigned short* xv = xk + (size_t)8388608;
    unsigned short* xo = xv + (size_t)8388608;
    probe<<<1, 64, 0, stream>>>((const unsigned int*)x, (const unsigned int*)mk, flags);
    dim3 gg(16, 128);
    gemm_bt<<<gg, 256, 0, stream>>>(x, wq, xq, 1024, 1024, flags, 1, 0);
    gemm_bt<<<gg, 256, 0, stream>>>(x, wk, xk, 1024, 1024, flags, 1, 0);
    gemm_bt<<<gg, 256, 0, stream>>>(x, wv, xv, 1024, 1024, flags, 1, 0);
    fattn_r2<<<dim3(128, NHEAD, 4), 64, 0, stream>>>(xq, xk, xv, mk, flags, xo);
    gemm_bt<<<gg, 256, 0, stream>>>(xo, wo, d_out, 1024, 1024, flags, 0, 1);
  }
}

// Round 6
// 555.926 us; speedup vs baseline: 3.4394x; 1.2607x over previous
//
#include <hip/hip_runtime.h>
#include <hip/hip_bf16.h>

#define S_LEN 2048
#define DIM   1024
#define NHEAD 16
#define HDIM  64

typedef __attribute__((ext_vector_type(8))) short bfrag;   // 8 bf16 = 4 VGPRs
typedef __attribute__((ext_vector_type(4))) float f32x4;   // MFMA C/D

#define MFMA(a,b,c) __builtin_amdgcn_mfma_f32_16x16x32_bf16((a),(b),(c),0,0,0)

__device__ __forceinline__ unsigned short f2bf(float x) {
  __hip_bfloat16 h = __float2bfloat16(x);
  return *reinterpret_cast<unsigned short*>(&h);
}

// async global->LDS, 16B per lane; LDS dest = wave-uniform base + lane*16
__device__ __forceinline__ void gll16(const unsigned short* g, unsigned short* l) {
  __builtin_amdgcn_global_load_lds(
      (const __attribute__((address_space(1))) unsigned int*)g,
      (__attribute__((address_space(3))) unsigned int*)l, 16, 0, 0);
}

// flags[0]: 0 = inputs bf16, 1 = inputs fp32
// flags[1]: mask mode 0=u8, 1=i32, 2=f32, 3=bf16
__global__ void probe(const unsigned int* __restrict__ x,
                      const unsigned int* __restrict__ mask,
                      int* __restrict__ flags) {
  if (threadIdx.x != 0) return;
  int insane = 0;
  for (int i = 0; i < 512; ++i) {
    unsigned int w = x[i];
    unsigned int e = (w >> 7) & 0xFFu;
    bool sane = (e >= 90u && e <= 160u) || ((w & 0x7FFFu) == 0u);
    insane += sane ? 0 : 1;
  }
  flags[0] = (insane > 128) ? 1 : 0;

  bool all01 = true, allu8 = true, allf32 = true, allbf = true;
  for (int i = 0; i < 1024; ++i) {
    unsigned int w = mask[i];
    all01  &= (w <= 1u);
    allu8  &= ((w & 0xFEFEFEFEu) == 0u);
    allf32 &= (w == 0u || w == 0x3F800000u);
    unsigned int lo = w & 0xFFFFu, hi = w >> 16;
    allbf  &= (lo == 0u || lo == 0x3F80u) && (hi == 0u || hi == 0x3F80u);
  }
  flags[1] = all01 ? 1 : (allu8 ? 0 : (allf32 ? 2 : (allbf ? 3 : 0)));
}

__device__ __forceinline__ bool mask_at(const void* mk, int mode, size_t idx) {
  switch (mode) {
    case 0:  return ((const unsigned char*)mk)[idx]  != 0;
    case 1:  return ((const int*)mk)[idx]            != 0;
    case 2:  return ((const unsigned int*)mk)[idx]   != 0u;
    default: return ((const unsigned short*)mk)[idx] != 0;
  }
}

// Convert fp32-or-bf16 source to bf16, 8 elems/thread.
__global__ __launch_bounds__(256) void cvt(const void* __restrict__ src,
                                           unsigned short* __restrict__ dst,
                                           int n8, const int* __restrict__ flags) {
  int i = blockIdx.x * 256 + threadIdx.x;
  if (i >= n8) return;
  if (flags[0]) {
    const float* p = (const float*)src + (size_t)i * 8;
    float4 a = *reinterpret_cast<const float4*>(p);
    float4 b = *reinterpret_cast<const float4*>(p + 4);
    bfrag r;
    r[0]=(short)f2bf(a.x); r[1]=(short)f2bf(a.y); r[2]=(short)f2bf(a.z); r[3]=(short)f2bf(a.w);
    r[4]=(short)f2bf(b.x); r[5]=(short)f2bf(b.y); r[6]=(short)f2bf(b.z); r[7]=(short)f2bf(b.w);
    *reinterpret_cast<bfrag*>(dst + (size_t)i * 8) = r;
  } else {
    *reinterpret_cast<bfrag*>(dst + (size_t)i * 8) =
        reinterpret_cast<const bfrag*>(src)[i];
  }
}

// Bit-pack mask (any mode) -> u64 per 64 keys via ballot.
__global__ __launch_bounds__(256) void bitmask(const void* __restrict__ mk,
                                               const int* __restrict__ flags,
                                               unsigned long long* __restrict__ mb) {
  size_t gid = (size_t)blockIdx.x * 256 + threadIdx.x;
  bool v = mask_at(mk, flags[1], gid);
  unsigned long long w = __ballot(v);
  if ((threadIdx.x & 63) == 0) mb[gid >> 6] = w;
}

// ---------------- m97-style GEMM: C(8192xN) = A @ Bt^T, bf16, K=1024 ----------------
// BM=BN=128, BK=32; 256 thr = 4 waves, wave -> 64x64 (4x4 MFMA 16x16x32).
// cMode: 1 head-split bf16, 2 plain dtype-per-flag, 3 fused-QKV head-split
__global__ __launch_bounds__(256) void gemm128(const unsigned short* __restrict__ A,
                                               const unsigned short* __restrict__ Bt,
                                               void* __restrict__ C,
                                               const int* __restrict__ flags,
                                               int aHsplit, int cMode) {
  __shared__ unsigned short As[128 * 32];
  __shared__ unsigned short Bs[128 * 32];
  const int t = threadIdx.x, lane = t & 63, wave = t >> 6;
  const int r16 = lane & 15, quad = lane >> 4;
  const int n0 = blockIdx.x * 128, m0 = blockIdx.y * 128;
  const int wm = (wave >> 1) * 64, wn = (wave & 1) * 64;
  const int arow = t >> 2, aseg = (t & 3) * 8;

  f32x4 acc[4][4];
#pragma unroll
  for (int i = 0; i < 4; ++i)
#pragma unroll
    for (int j = 0; j < 4; ++j) acc[i][j] = (f32x4){0.f, 0.f, 0.f, 0.f};

  for (int k0 = 0; k0 < 1024; k0 += 32) {
    __syncthreads();
#pragma unroll
    for (int rr = 0; rr < 2; ++rr) {
      const int m = m0 + rr * 64 + arow;
      const int k = k0 + aseg;
      const unsigned short* ga;
      if (aHsplit) ga = A + ((size_t)(((m >> 11) << 4) + (k >> 6)) * 2048 + (m & 2047)) * 64 + (k & 63);
      else         ga = A + (size_t)m * 1024 + k;
      gll16(ga, As + rr * 2048 + wave * 512);
      const unsigned short* gb = Bt + (size_t)(n0 + rr * 64 + arow) * 1024 + k0 + aseg;
      gll16(gb, Bs + rr * 2048 + wave * 512);
    }
    __syncthreads();

    bfrag af[4], bf[4];
#pragma unroll
    for (int i = 0; i < 4; ++i)
      af[i] = *reinterpret_cast<const bfrag*>(&As[(wm + i * 16 + r16) * 32 + quad * 8]);
#pragma unroll
    for (int j = 0; j < 4; ++j)
      bf[j] = *reinterpret_cast<const bfrag*>(&Bs[(wn + j * 16 + r16) * 32 + quad * 8]);
#pragma unroll
    for (int i = 0; i < 4; ++i)
#pragma unroll
      for (int j = 0; j < 4; ++j)
        acc[i][j] = MFMA(af[i], bf[j], acc[i][j]);
  }

  const int oF = (cMode == 2) ? flags[0] : 0;
#pragma unroll
  for (int i = 0; i < 4; ++i)
#pragma unroll
    for (int j = 0; j < 4; ++j)
#pragma unroll
      for (int r = 0; r < 4; ++r) {
        const int m = m0 + wm + i * 16 + quad * 4 + r;
        const int n = n0 + wn + j * 16 + r16;
        const float v = acc[i][j][r];
        if (cMode == 3) {
          const int region = n >> 10, nn = n & 1023;
          const size_t idx = (size_t)region * 8388608 +
              ((size_t)((m >> 11) * NHEAD + (nn >> 6)) * 2048 + (m & 2047)) * 64 + (nn & 63);
          ((unsigned short*)C)[idx] = f2bf(v);
        } else if (cMode == 1) {
          const size_t idx = ((size_t)((m >> 11) * NHEAD + (n >> 6)) * 2048 + (m & 2047)) * 64 + (n & 63);
          ((unsigned short*)C)[idx] = f2bf(v);
        } else {
          const size_t idx = (size_t)m * 1024 + n;
          if (oF) ((float*)C)[idx] = v;
          else    ((unsigned short*)C)[idx] = f2bf(v);
        }
      }
}

// xvH [bh][s][64] -> xvT [bh][64][s], 64x64 tiles through LDS.
__global__ __launch_bounds__(256) void transposeV(const unsigned short* __restrict__ xvH,
                                                  unsigned short* __restrict__ xvT) {
  __shared__ unsigned short Ts[64 * 80];
  const int t = threadIdx.x;
  const int s0 = blockIdx.x * 64, bh = blockIdx.y;
  const int sr = t >> 3, seg = (t & 7) * 8;   // sr in [0,32)
#pragma unroll
  for (int rr = 0; rr < 2; ++rr) {
    const int s = rr * 32 + sr;
    bfrag v = *reinterpret_cast<const bfrag*>(xvH + ((size_t)bh * 2048 + s0 + s) * 64 + seg);
#pragma unroll
    for (int j = 0; j < 8; ++j) Ts[(seg + j) * 80 + s] = (unsigned short)v[j];
  }
  __syncthreads();
#pragma unroll
  for (int rr = 0; rr < 2; ++rr) {
    const int d = rr * 32 + sr;
    bfrag o = *reinterpret_cast<const bfrag*>(&Ts[d * 80 + seg]);
    *reinterpret_cast<bfrag*>(xvT + ((size_t)bh * 64 + d) * 2048 + s0 + seg) = o;
  }
}

// ---------------- fattn v4 ----------------
// 4 waves x 32 q-rows (128 q/block), 64 keys/step.
// S^T = MFMA(K,Q) orientation; fixed-max softmax (no running max/alpha);
// XOR-swizzled K/V LDS; Ps stride 72 (2-way writes); per-lane deferred l-sum.
__global__ __launch_bounds__(256) void fattn(const unsigned short* __restrict__ qH,
                                             const unsigned short* __restrict__ kH,
                                             const unsigned short* __restrict__ vT,
                                             const unsigned long long* __restrict__ mb,
                                             unsigned short* __restrict__ oH) {
  __shared__ unsigned short Ks[64 * 64];
  __shared__ unsigned short Vs[64 * 64];
  __shared__ unsigned short Ps[4][16 * 72];
  const int t = threadIdx.x, lane = t & 63, wave = t >> 6;
  const int r16 = lane & 15, quad = lane >> 4;
  const int q0 = blockIdx.x * 128;
  const int h = blockIdx.y, b = blockIdx.z;
  const int bh = b * NHEAD + h;
  const int qw = q0 + wave * 32;
  const size_t hbase = (size_t)bh * S_LEN;

  // Q fragments: 2 q-subtiles x 2 d-halves (B-operand layout == A layout)
  bfrag aq[2][2];
#pragma unroll
  for (int qt = 0; qt < 2; ++qt)
#pragma unroll
    for (int hh = 0; hh < 2; ++hh)
      aq[qt][hh] = *reinterpret_cast<const bfrag*>(
          qH + (hbase + qw + qt * 16 + r16) * 64 + hh * 32 + quad * 8);

  f32x4 o[2][4];
#pragma unroll
  for (int qt = 0; qt < 2; ++qt)
#pragma unroll
    for (int i = 0; i < 4; ++i) o[qt][i] = (f32x4){0.f, 0.f, 0.f, 0.f};
  float lsum[2] = {0.f, 0.f};

  const int srow = lane >> 3;            // 0..7
  const int sg   = (lane & 7) ^ srow;    // swizzled global chunk

  for (int kb = 0; kb < S_LEN; kb += 64) {
    __syncthreads();
#pragma unroll
    for (int rr = 0; rr < 2; ++rr) {
      const int row = rr * 32 + wave * 8 + srow;
      gll16(kH + (hbase + kb + row) * 64 + sg * 8, Ks + rr * 2048 + wave * 512);
      gll16(vT + ((size_t)bh * 64 + row) * 2048 + kb + sg * 8, Vs + rr * 2048 + wave * 512);
    }
    __syncthreads();

    bfrag kf[4][2], vf[4][2];
#pragma unroll
    for (int t4 = 0; t4 < 4; ++t4)
#pragma unroll
      for (int hh = 0; hh < 2; ++hh) {
        const int ch = (hh * 4 + quad) ^ (r16 & 7);
        kf[t4][hh] = *reinterpret_cast<const bfrag*>(&Ks[(t4 * 16 + r16) * 64 + ch * 8]);
        vf[t4][hh] = *reinterpret_cast<const bfrag*>(&Vs[(t4 * 16 + r16) * 64 + ch * 8]);
      }

#pragma unroll
    for (int qt = 0; qt < 2; ++qt) {
      f32x4 s[4];
#pragma unroll
      for (int t4 = 0; t4 < 4; ++t4) {
        f32x4 z = (f32x4){0.f, 0.f, 0.f, 0.f};
        z = MFMA(kf[t4][0], aq[qt][0], z);   // S^T[key][q]
        z = MFMA(kf[t4][1], aq[qt][1], z);
        s[t4] = z;
      }
      const unsigned long long w =
          mb[((size_t)b * S_LEN + qw + qt * 16 + r16) * 32 + (kb >> 6)];

      float p[4][4];
#pragma unroll
      for (int t4 = 0; t4 < 4; ++t4)
#pragma unroll
        for (int r = 0; r < 4; ++r) {
          const bool keep = (w >> (t4 * 16 + quad * 4 + r)) & 1ull;
          const float e = __builtin_amdgcn_exp2f(fminf(s[t4][r] * 0.18033688f, 80.f));
          const float pv = keep ? e : 0.f;
          p[t4][r] = pv;
          lsum[qt] += pv;
        }
      // pack pairs -> dword writes, stride-72 rows (q = r16)
#pragma unroll
      for (int t4 = 0; t4 < 4; ++t4)
#pragma unroll
        for (int r = 0; r < 4; r += 2) {
          const unsigned int dw =
              (unsigned int)f2bf(p[t4][r]) | ((unsigned int)f2bf(p[t4][r + 1]) << 16);
          *reinterpret_cast<unsigned int*>(
              &Ps[wave][r16 * 72 + t4 * 16 + quad * 4 + r]) = dw;
        }
      __asm__ volatile("s_waitcnt lgkmcnt(0)" ::: "memory");

      bfrag pa0 = *reinterpret_cast<const bfrag*>(&Ps[wave][r16 * 72 + quad * 8]);
      bfrag pa1 = *reinterpret_cast<const bfrag*>(&Ps[wave][r16 * 72 + 32 + quad * 8]);
#pragma unroll
      for (int t4 = 0; t4 < 4; ++t4) {
        o[qt][t4] = MFMA(pa0, vf[t4][0], o[qt][t4]);
        o[qt][t4] = MFMA(pa1, vf[t4][1], o[qt][t4]);
      }
    }
  }

#pragma unroll
  for (int qt = 0; qt < 2; ++qt) {
    float l = lsum[qt];
    l += __shfl_xor(l, 16, 64);
    l += __shfl_xor(l, 32, 64);   // all quads now hold total for q = qw+qt*16+r16
    float rl[4];
#pragma unroll
    for (int r = 0; r < 4; ++r)
      rl[r] = 1.f / fmaxf(__shfl(l, quad * 4 + r, 64), 1e-30f);
#pragma unroll
    for (int t4 = 0; t4 < 4; ++t4)
#pragma unroll
      for (int r = 0; r < 4; ++r)
        oH[(hbase + qw + qt * 16 + quad * 4 + r) * 64 + t4 * 16 + r16] =
            f2bf(o[qt][t4][r] * rl[r]);
  }
}

// ======================= round-2 fallback (small ws) =======================
template<bool F32>
__device__ __forceinline__ bfrag load8(const void* base, size_t idx) {
  if constexpr (F32) {
    const float* p = (const float*)base + idx;
    float4 u = *reinterpret_cast<const float4*>(p);
    float4 v = *reinterpret_cast<const float4*>(p + 4);
    bfrag r;
    r[0]=(short)f2bf(u.x); r[1]=(short)f2bf(u.y); r[2]=(short)f2bf(u.z); r[3]=(short)f2bf(u.w);
    r[4]=(short)f2bf(v.x); r[5]=(short)f2bf(v.y); r[6]=(short)f2bf(v.z); r[7]=(short)f2bf(v.w);
    return r;
  } else {
    return *reinterpret_cast<const bfrag*>((const unsigned short*)base + idx);
  }
}

template<bool AF32, bool BF32>
__device__ __forceinline__ void gemm_body(const void* __restrict__ A, const void* __restrict__ Bt,
                                          void* __restrict__ C, int N, int K, bool outF32) {
  const int lane = threadIdx.x & 63, wave = threadIdx.x >> 6;
  const int r16 = lane & 15, quad = lane >> 4;
  const int m0 = (blockIdx.y * 4 + wave) * 16, n0 = blockIdx.x * 64;
  f32x4 acc[4];
#pragma unroll
  for (int i = 0; i < 4; ++i) acc[i] = (f32x4){0.f,0.f,0.f,0.f};
  const size_t aoff = (size_t)(m0 + r16) * K + quad * 8;
  const size_t boff = (size_t)(n0 + r16) * K + quad * 8;
  for (int k0 = 0; k0 < K; k0 += 32) {
    bfrag a = load8<AF32>(A, aoff + k0);
#pragma unroll
    for (int tt = 0; tt < 4; ++tt) {
      bfrag bb = load8<BF32>(Bt, boff + (size_t)tt * 16 * K + k0);
      acc[tt] = MFMA(a, bb, acc[tt]);
    }
  }
#pragma unroll
  for (int tt = 0; tt < 4; ++tt)
#pragma unroll
    for (int r = 0; r < 4; ++r) {
      const size_t ci = (size_t)(m0 + quad * 4 + r) * N + n0 + tt * 16 + r16;
      if (outF32) ((float*)C)[ci] = acc[tt][r];
      else        ((unsigned short*)C)[ci] = f2bf(acc[tt][r]);
    }
}

__global__ __launch_bounds__(256) void gemm_bt(const void* A, const void* Bt, void* C,
                                               int N, int K, const int* flags,
                                               int aFollows, int outFollows) {
  const int f = flags[0];
  const bool aF = (aFollows != 0) && (f != 0);
  const bool oF = (outFollows != 0) && (f != 0);
  if (f) { if (aF) gemm_body<true, true>(A, Bt, C, N, K, oF);
           else    gemm_body<false, true>(A, Bt, C, N, K, oF); }
  else     gemm_body<false, false>(A, Bt, C, N, K, oF);
}

__global__ __launch_bounds__(64) void fattn_r2(const unsigned short* __restrict__ xq,
                                               const unsigned short* __restrict__ xk,
                                               const unsigned short* __restrict__ xv,
                                               const void* __restrict__ mk,
                                               const int* __restrict__ flags,
                                               unsigned short* __restrict__ xo) {
  __shared__ unsigned short smemP[16 * 32];
  const int lane = threadIdx.x, r16 = lane & 15, quad = lane >> 4;
  const int q0 = blockIdx.x * 16, h = blockIdx.y, b = blockIdx.z;
  const int mmode = flags[1];
  const size_t base = (size_t)b * S_LEN * DIM + (size_t)h * HDIM;
  const size_t mbase = (size_t)b * S_LEN * S_LEN;
  bfrag aq0 = *reinterpret_cast<const bfrag*>(xq + base + (size_t)(q0 + r16) * DIM + quad * 8);
  bfrag aq1 = *reinterpret_cast<const bfrag*>(xq + base + (size_t)(q0 + r16) * DIM + 32 + quad * 8);
  f32x4 o[4];
#pragma unroll
  for (int i = 0; i < 4; ++i) o[i] = (f32x4){0.f,0.f,0.f,0.f};
  float m_r[4] = {-1e30f,-1e30f,-1e30f,-1e30f}, l_r[4] = {0.f,0.f,0.f,0.f};
  for (int kb = 0; kb < S_LEN; kb += 32) {
    const unsigned short* k0p = xk + base + (size_t)(kb + r16) * DIM + quad * 8;
    const unsigned short* k1p = k0p + (size_t)16 * DIM;
    f32x4 s0 = (f32x4){0.f,0.f,0.f,0.f}, s1 = (f32x4){0.f,0.f,0.f,0.f};
    s0 = MFMA(aq0, *reinterpret_cast<const bfrag*>(k0p), s0);
    s0 = MFMA(aq1, *reinterpret_cast<const bfrag*>(k0p + 32), s0);
    s1 = MFMA(aq0, *reinterpret_cast<const bfrag*>(k1p), s1);
    s1 = MFMA(aq1, *reinterpret_cast<const bfrag*>(k1p + 32), s1);
    float l0[4], l1[4], tmax[4];
#pragma unroll
    for (int r = 0; r < 4; ++r) {
      const size_t mrow = mbase + (size_t)(q0 + quad * 4 + r) * S_LEN + kb;
      l0[r] = mask_at(mk, mmode, mrow + r16) ? s0[r] * 0.125f : -1e30f;
      l1[r] = mask_at(mk, mmode, mrow + 16 + r16) ? s1[r] * 0.125f : -1e30f;
      tmax[r] = fmaxf(l0[r], l1[r]);
    }
#pragma unroll
    for (int off = 1; off < 16; off <<= 1)
#pragma unroll
      for (int r = 0; r < 4; ++r) tmax[r] = fmaxf(tmax[r], __shfl_xor(tmax[r], off, 64));
    float p0[4], p1[4], rsum[4];
#pragma unroll
    for (int r = 0; r < 4; ++r) {
      const float mnew = fmaxf(m_r[r], tmax[r]);
      const float alpha = __expf(m_r[r] - mnew);
      m_r[r] = mnew;
      p0[r] = (l0[r] <= -1e29f) ? 0.f : __expf(l0[r] - mnew);
      p1[r] = (l1[r] <= -1e29f) ? 0.f : __expf(l1[r] - mnew);
      rsum[r] = p0[r] + p1[r];
      l_r[r] *= alpha;
#pragma unroll
      for (int tt = 0; tt < 4; ++tt) o[tt][r] *= alpha;
    }
#pragma unroll
    for (int off = 1; off < 16; off <<= 1)
#pragma unroll
      for (int r = 0; r < 4; ++r) rsum[r] += __shfl_xor(rsum[r], off, 64);
#pragma unroll
    for (int r = 0; r < 4; ++r) l_r[r] += rsum[r];
#pragma unroll
    for (int r = 0; r < 4; ++r) {
      smemP[(quad * 4 + r) * 32 + r16] = f2bf(p0[r]);
      smemP[(quad * 4 + r) * 32 + 16 + r16] = f2bf(p1[r]);
    }
    __syncthreads();
    bfrag apf = *reinterpret_cast<const bfrag*>(&smemP[r16 * 32 + quad * 8]);
    const unsigned short* vbase = xv + base + (size_t)(kb + quad * 8) * DIM + r16;
#pragma unroll
    for (int tt = 0; tt < 4; ++tt) {
      bfrag bv;
#pragma unroll
      for (int j = 0; j < 8; ++j) bv[j] = (short)vbase[(size_t)j * DIM + tt * 16];
      o[tt] = MFMA(apf, bv, o[tt]);
    }
    __syncthreads();
  }
#pragma unroll
  for (int tt = 0; tt < 4; ++tt)
#pragma unroll
    for (int r = 0; r < 4; ++r)
      xo[base + (size_t)(q0 + quad * 4 + r) * DIM + tt * 16 + r16] = f2bf(o[tt][r] / l_r[r]);
}

extern "C" void kernel_launch(void* const* d_in, const int* in_sizes, int n_in,
                              void* d_out, int out_size, void* d_ws, size_t ws_size,
                              hipStream_t stream) {
  const void* x  = d_in[0];
  const void* mk = d_in[1];
  const void* wq = d_in[2];
  const void* wk = d_in[3];
  const void* wv = d_in[4];
  const void* wo = d_in[5];

  const size_t MiB = 1048576;
  const size_t NEED = 4096 + 90 * MiB;

  if (ws_size >= NEED) {
    char* p = (char*)d_ws;
    int* flags = (int*)p;                       p += 4096;
    unsigned short* xb  = (unsigned short*)p;   p += 16 * MiB;
    unsigned short* wqb = (unsigned short*)p;   p += 2 * MiB;   // wq/wk/wv contiguous
    unsigned short* wkb = (unsigned short*)p;   p += 2 * MiB;
    unsigned short* wvb = (unsigned short*)p;   p += 2 * MiB;
    unsigned short* wob = (unsigned short*)p;   p += 2 * MiB;
    unsigned long long* mb = (unsigned long long*)p; p += 2 * MiB;
    unsigned short* xqH = (unsigned short*)p;   p += 16 * MiB;  // xq/xk/xv contiguous
    unsigned short* xkH = (unsigned short*)p;   p += 16 * MiB;
    unsigned short* xvH = (unsigned short*)p;   p += 16 * MiB;  // reused as xoH
    unsigned short* xvT = (unsigned short*)p;   p += 16 * MiB;
    unsigned short* xoH = xvH;  // xvH dead after transposeV

    probe<<<1, 64, 0, stream>>>((const unsigned int*)x, (const unsigned int*)mk, flags);
    cvt<<<4096, 256, 0, stream>>>(x,  xb,  1048576, flags);
    cvt<<<512,  256, 0, stream>>>(wq, wqb, 131072, flags);
    cvt<<<512,  256, 0, stream>>>(wk, wkb, 131072, flags);
    cvt<<<512,  256, 0, stream>>>(wv, wvb, 131072, flags);
    cvt<<<512,  256, 0, stream>>>(wo, wob, 131072, flags);
    bitmask<<<65536, 256, 0, stream>>>(mk, flags, mb);

    // fused QKV projection: N = 3072 (wq/wk/wv rows contiguous)
    gemm128<<<dim3(24, 64), 256, 0, stream>>>(xb, wqb, xqH, flags, 0, 3);
    transposeV<<<dim3(32, 64), 256, 0, stream>>>(xvH, xvT);
    fattn<<<dim3(16, NHEAD, 4), 256, 0, stream>>>(xqH, xkH, xvT, mb, xoH);
    gemm128<<<dim3(8, 64), 256, 0, stream>>>(xoH, wob, d_out, flags, 1, 2);
  } else {
    // round-2 fallback
    int* flags = (int*)d_ws;
    unsigned short* xq = (unsigned short*)((char*)d_ws + 256);
    unsigned short* xk = xq + (size_t)8388608;
    unsigned short* xv = xk + (size_t)8388608;
    unsigned short* xo = xv + (size_t)8388608;
    probe<<<1, 64, 0, stream>>>((const unsigned int*)x, (const unsigned int*)mk, flags);
    dim3 gg(16, 128);
    gemm_bt<<<gg, 256, 0, stream>>>(x, wq, xq, 1024, 1024, flags, 1, 0);
    gemm_bt<<<gg, 256, 0, stream>>>(x, wk, xk, 1024, 1024, flags, 1, 0);
    gemm_bt<<<gg, 256, 0, stream>>>(x, wv, xv, 1024, 1024, flags, 1, 0);
    fattn_r2<<<dim3(128, NHEAD, 4), 64, 0, stream>>>(xq, xk, xv, mk, flags, xo);
    gemm_bt<<<gg, 256, 0, stream>>>(xo, wo, d_out, 1024, 1024, flags, 0, 1);
  }
}

// Round 7
// 459.401 us; speedup vs baseline: 4.1621x; 1.2101x over previous
//
#include <hip/hip_runtime.h>
#include <hip/hip_bf16.h>

#define S_LEN 2048
#define DIM   1024
#define NHEAD 16
#define HDIM  64

typedef __attribute__((ext_vector_type(8))) short bfrag;   // 8 bf16 = 4 VGPRs
typedef __attribute__((ext_vector_type(4))) float f32x4;   // MFMA C/D

#define MFMA(a,b,c) __builtin_amdgcn_mfma_f32_16x16x32_bf16((a),(b),(c),0,0,0)

__device__ __forceinline__ unsigned short f2bf(float x) {
  __hip_bfloat16 h = __float2bfloat16(x);
  return *reinterpret_cast<unsigned short*>(&h);
}

// async global->LDS, 16B per lane; LDS dest = wave-uniform base + lane*16
__device__ __forceinline__ void gll16(const unsigned short* g, unsigned short* l) {
  __builtin_amdgcn_global_load_lds(
      (const __attribute__((address_space(1))) unsigned int*)g,
      (__attribute__((address_space(3))) unsigned int*)l, 16, 0, 0);
}

// flags[0]: 0 = inputs bf16, 1 = inputs fp32
// flags[1]: mask mode 0=u8, 1=i32, 2=f32, 3=bf16
// 64-lane parallel (round-6 version was 1 serial thread).
__global__ void probe(const unsigned int* __restrict__ x,
                      const unsigned int* __restrict__ mask,
                      int* __restrict__ flags) {
  const int lane = threadIdx.x;
  int insane = 0;
  for (int i = lane; i < 512; i += 64) {
    unsigned int w = x[i];
    unsigned int e = (w >> 7) & 0xFFu;
    bool sane = (e >= 90u && e <= 160u) || ((w & 0x7FFFu) == 0u);
    insane += sane ? 0 : 1;
  }
  bool all01 = true, allu8 = true, allf32 = true, allbf = true;
  for (int i = lane; i < 1024; i += 64) {
    unsigned int w = mask[i];
    all01  &= (w <= 1u);
    allu8  &= ((w & 0xFEFEFEFEu) == 0u);
    allf32 &= (w == 0u || w == 0x3F800000u);
    unsigned int lo = w & 0xFFFFu, hi = w >> 16;
    allbf  &= (lo == 0u || lo == 0x3F80u) && (hi == 0u || hi == 0x3F80u);
  }
#pragma unroll
  for (int off = 1; off < 64; off <<= 1) insane += __shfl_xor(insane, off, 64);
  const unsigned long long full = ~0ull;
  const bool g01  = __ballot(all01)  == full;
  const bool gu8  = __ballot(allu8)  == full;
  const bool gf32 = __ballot(allf32) == full;
  const bool gbf  = __ballot(allbf)  == full;
  if (lane == 0) {
    flags[0] = (insane > 128) ? 1 : 0;
    flags[1] = g01 ? 1 : (gu8 ? 0 : (gf32 ? 2 : (gbf ? 3 : 0)));
  }
}

__device__ __forceinline__ bool mask_at(const void* mk, int mode, size_t idx) {
  switch (mode) {
    case 0:  return ((const unsigned char*)mk)[idx]  != 0;
    case 1:  return ((const int*)mk)[idx]            != 0;
    case 2:  return ((const unsigned int*)mk)[idx]   != 0u;
    default: return ((const unsigned short*)mk)[idx] != 0;
  }
}

// Convert fp32-or-bf16 source to bf16, 8 elems/thread.
__global__ __launch_bounds__(256) void cvt(const void* __restrict__ src,
                                           unsigned short* __restrict__ dst,
                                           int n8, const int* __restrict__ flags) {
  int i = blockIdx.x * 256 + threadIdx.x;
  if (i >= n8) return;
  if (flags[0]) {
    const float* p = (const float*)src + (size_t)i * 8;
    float4 a = *reinterpret_cast<const float4*>(p);
    float4 b = *reinterpret_cast<const float4*>(p + 4);
    bfrag r;
    r[0]=(short)f2bf(a.x); r[1]=(short)f2bf(a.y); r[2]=(short)f2bf(a.z); r[3]=(short)f2bf(a.w);
    r[4]=(short)f2bf(b.x); r[5]=(short)f2bf(b.y); r[6]=(short)f2bf(b.z); r[7]=(short)f2bf(b.w);
    *reinterpret_cast<bfrag*>(dst + (size_t)i * 8) = r;
  } else {
    *reinterpret_cast<bfrag*>(dst + (size_t)i * 8) =
        reinterpret_cast<const bfrag*>(src)[i];
  }
}

// Bit-pack mask (any mode) -> u64 per 64 keys via ballot.
__global__ __launch_bounds__(256) void bitmask(const void* __restrict__ mk,
                                               const int* __restrict__ flags,
                                               unsigned long long* __restrict__ mb) {
  size_t gid = (size_t)blockIdx.x * 256 + threadIdx.x;
  bool v = mask_at(mk, flags[1], gid);
  unsigned long long w = __ballot(v);
  if ((threadIdx.x & 63) == 0) mb[gid >> 6] = w;
}

// ---------------- m97-style GEMM: C(8192xN) = A @ Bt^T, bf16, K=1024 ----------------
// BM=BN=128, BK=32; 256 thr = 4 waves, wave -> 64x64 (4x4 MFMA 16x16x32).
// cMode: 1 head-split bf16, 2 plain dtype-per-flag, 3 fused-QKV head-split
__global__ __launch_bounds__(256) void gemm128(const unsigned short* __restrict__ A,
                                               const unsigned short* __restrict__ Bt,
                                               void* __restrict__ C,
                                               const int* __restrict__ flags,
                                               int aHsplit, int cMode) {
  __shared__ unsigned short As[128 * 32];
  __shared__ unsigned short Bs[128 * 32];
  const int t = threadIdx.x, lane = t & 63, wave = t >> 6;
  const int r16 = lane & 15, quad = lane >> 4;
  const int n0 = blockIdx.x * 128, m0 = blockIdx.y * 128;
  const int wm = (wave >> 1) * 64, wn = (wave & 1) * 64;
  const int arow = t >> 2, aseg = (t & 3) * 8;

  f32x4 acc[4][4];
#pragma unroll
  for (int i = 0; i < 4; ++i)
#pragma unroll
    for (int j = 0; j < 4; ++j) acc[i][j] = (f32x4){0.f, 0.f, 0.f, 0.f};

  for (int k0 = 0; k0 < 1024; k0 += 32) {
    __syncthreads();
#pragma unroll
    for (int rr = 0; rr < 2; ++rr) {
      const int m = m0 + rr * 64 + arow;
      const int k = k0 + aseg;
      const unsigned short* ga;
      if (aHsplit) ga = A + ((size_t)(((m >> 11) << 4) + (k >> 6)) * 2048 + (m & 2047)) * 64 + (k & 63);
      else         ga = A + (size_t)m * 1024 + k;
      gll16(ga, As + rr * 2048 + wave * 512);
      const unsigned short* gb = Bt + (size_t)(n0 + rr * 64 + arow) * 1024 + k0 + aseg;
      gll16(gb, Bs + rr * 2048 + wave * 512);
    }
    __syncthreads();

    bfrag af[4], bf[4];
#pragma unroll
    for (int i = 0; i < 4; ++i)
      af[i] = *reinterpret_cast<const bfrag*>(&As[(wm + i * 16 + r16) * 32 + quad * 8]);
#pragma unroll
    for (int j = 0; j < 4; ++j)
      bf[j] = *reinterpret_cast<const bfrag*>(&Bs[(wn + j * 16 + r16) * 32 + quad * 8]);
#pragma unroll
    for (int i = 0; i < 4; ++i)
#pragma unroll
      for (int j = 0; j < 4; ++j)
        acc[i][j] = MFMA(af[i], bf[j], acc[i][j]);
  }

  const int oF = (cMode == 2) ? flags[0] : 0;
#pragma unroll
  for (int i = 0; i < 4; ++i)
#pragma unroll
    for (int j = 0; j < 4; ++j)
#pragma unroll
      for (int r = 0; r < 4; ++r) {
        const int m = m0 + wm + i * 16 + quad * 4 + r;
        const int n = n0 + wn + j * 16 + r16;
        const float v = acc[i][j][r];
        if (cMode == 3) {
          const int region = n >> 10, nn = n & 1023;
          const size_t idx = (size_t)region * 8388608 +
              ((size_t)((m >> 11) * NHEAD + (nn >> 6)) * 2048 + (m & 2047)) * 64 + (nn & 63);
          ((unsigned short*)C)[idx] = f2bf(v);
        } else if (cMode == 1) {
          const size_t idx = ((size_t)((m >> 11) * NHEAD + (n >> 6)) * 2048 + (m & 2047)) * 64 + (n & 63);
          ((unsigned short*)C)[idx] = f2bf(v);
        } else {
          const size_t idx = (size_t)m * 1024 + n;
          if (oF) ((float*)C)[idx] = v;
          else    ((unsigned short*)C)[idx] = f2bf(v);
        }
      }
}

// xvH [bh][s][64] -> xvT [bh][64][s], 64x64 tiles through LDS.
__global__ __launch_bounds__(256) void transposeV(const unsigned short* __restrict__ xvH,
                                                  unsigned short* __restrict__ xvT) {
  __shared__ unsigned short Ts[64 * 80];
  const int t = threadIdx.x;
  const int s0 = blockIdx.x * 64, bh = blockIdx.y;
  const int sr = t >> 3, seg = (t & 7) * 8;   // sr in [0,32)
#pragma unroll
  for (int rr = 0; rr < 2; ++rr) {
    const int s = rr * 32 + sr;
    bfrag v = *reinterpret_cast<const bfrag*>(xvH + ((size_t)bh * 2048 + s0 + s) * 64 + seg);
#pragma unroll
    for (int j = 0; j < 8; ++j) Ts[(seg + j) * 80 + s] = (unsigned short)v[j];
  }
  __syncthreads();
#pragma unroll
  for (int rr = 0; rr < 2; ++rr) {
    const int d = rr * 32 + sr;
    bfrag o = *reinterpret_cast<const bfrag*>(&Ts[d * 80 + seg]);
    *reinterpret_cast<bfrag*>(xvT + ((size_t)bh * 64 + d) * 2048 + s0 + seg) = o;
  }
}

// ---------------- fattn v5 ----------------
// 1-D grid, bid = qidx*64 + bh  =>  bid%8 == bh%8: all q-blocks of a (b,h)
// land on one XCD (K/V stay L2-resident). Double-buffered K/V staging:
// loads for step k+1 issued right after the barrier, drained at the next one.
__global__ __launch_bounds__(256) void fattn(const unsigned short* __restrict__ qH,
                                             const unsigned short* __restrict__ kH,
                                             const unsigned short* __restrict__ vT,
                                             const unsigned long long* __restrict__ mb,
                                             unsigned short* __restrict__ oH) {
  __shared__ unsigned short Ks[2][64 * 64];
  __shared__ unsigned short Vs[2][64 * 64];
  __shared__ unsigned short Ps[4][16 * 72];
  const int t = threadIdx.x, lane = t & 63, wave = t >> 6;
  const int r16 = lane & 15, quad = lane >> 4;
  const int bid = blockIdx.x;
  const int bh = bid & 63, qidx = bid >> 6;
  const int b = bh >> 4;
  const int qw = qidx * 128 + wave * 32;
  const size_t hbase = (size_t)bh * S_LEN;

  // Q fragments: 2 q-subtiles x 2 d-halves (B-operand layout == A layout)
  bfrag aq[2][2];
#pragma unroll
  for (int qt = 0; qt < 2; ++qt)
#pragma unroll
    for (int hh = 0; hh < 2; ++hh)
      aq[qt][hh] = *reinterpret_cast<const bfrag*>(
          qH + (hbase + qw + qt * 16 + r16) * 64 + hh * 32 + quad * 8);

  f32x4 o[2][4];
#pragma unroll
  for (int qt = 0; qt < 2; ++qt)
#pragma unroll
    for (int i = 0; i < 4; ++i) o[qt][i] = (f32x4){0.f, 0.f, 0.f, 0.f};
  float lsum[2] = {0.f, 0.f};

  const int srow = lane >> 3;            // 0..7
  const int sg   = (lane & 7) ^ srow;    // swizzled global chunk

  // stage K/V tile for key-block kb into buffer buf
  auto stage = [&](int buf, int kb) {
#pragma unroll
    for (int rr = 0; rr < 2; ++rr) {
      const int row = rr * 32 + wave * 8 + srow;
      gll16(kH + (hbase + kb + row) * 64 + sg * 8, &Ks[buf][rr * 2048 + wave * 512]);
      gll16(vT + ((size_t)bh * 64 + row) * 2048 + kb + sg * 8, &Vs[buf][rr * 2048 + wave * 512]);
    }
  };

  stage(0, 0);
  int cur = 0;

  for (int kb = 0; kb < S_LEN; kb += 64) {
    __syncthreads();                       // drains own vmcnt -> buf[cur] ready
    if (kb + 64 < S_LEN) stage(cur ^ 1, kb + 64);   // prefetch next tile

    bfrag kf[4][2], vf[4][2];
#pragma unroll
    for (int t4 = 0; t4 < 4; ++t4)
#pragma unroll
      for (int hh = 0; hh < 2; ++hh) {
        const int ch = (hh * 4 + quad) ^ (r16 & 7);
        kf[t4][hh] = *reinterpret_cast<const bfrag*>(&Ks[cur][(t4 * 16 + r16) * 64 + ch * 8]);
        vf[t4][hh] = *reinterpret_cast<const bfrag*>(&Vs[cur][(t4 * 16 + r16) * 64 + ch * 8]);
      }

#pragma unroll
    for (int qt = 0; qt < 2; ++qt) {
      f32x4 s[4];
#pragma unroll
      for (int t4 = 0; t4 < 4; ++t4) {
        f32x4 z = (f32x4){0.f, 0.f, 0.f, 0.f};
        z = MFMA(kf[t4][0], aq[qt][0], z);   // S^T[key][q]
        z = MFMA(kf[t4][1], aq[qt][1], z);
        s[t4] = z;
      }
      const unsigned long long w =
          mb[((size_t)b * S_LEN + qw + qt * 16 + r16) * 32 + (kb >> 6)];

      float p[4][4];
#pragma unroll
      for (int t4 = 0; t4 < 4; ++t4)
#pragma unroll
        for (int r = 0; r < 4; ++r) {
          const bool keep = (w >> (t4 * 16 + quad * 4 + r)) & 1ull;
          const float e = __builtin_amdgcn_exp2f(s[t4][r] * 0.18033688f);
          const float pv = keep ? e : 0.f;
          p[t4][r] = pv;
          lsum[qt] += pv;
        }
      // pack pairs -> dword writes, stride-72 rows (q = r16)
#pragma unroll
      for (int t4 = 0; t4 < 4; ++t4)
#pragma unroll
        for (int r = 0; r < 4; r += 2) {
          const unsigned int dw =
              (unsigned int)f2bf(p[t4][r]) | ((unsigned int)f2bf(p[t4][r + 1]) << 16);
          *reinterpret_cast<unsigned int*>(
              &Ps[wave][r16 * 72 + t4 * 16 + quad * 4 + r]) = dw;
        }
      __asm__ volatile("s_waitcnt lgkmcnt(0)" ::: "memory");

      bfrag pa0 = *reinterpret_cast<const bfrag*>(&Ps[wave][r16 * 72 + quad * 8]);
      bfrag pa1 = *reinterpret_cast<const bfrag*>(&Ps[wave][r16 * 72 + 32 + quad * 8]);
#pragma unroll
      for (int t4 = 0; t4 < 4; ++t4) {
        o[qt][t4] = MFMA(pa0, vf[t4][0], o[qt][t4]);
        o[qt][t4] = MFMA(pa1, vf[t4][1], o[qt][t4]);
      }
    }
    cur ^= 1;
  }

#pragma unroll
  for (int qt = 0; qt < 2; ++qt) {
    float l = lsum[qt];
    l += __shfl_xor(l, 16, 64);
    l += __shfl_xor(l, 32, 64);   // all quads now hold total for q = qw+qt*16+r16
    float rl[4];
#pragma unroll
    for (int r = 0; r < 4; ++r)
      rl[r] = 1.f / fmaxf(__shfl(l, quad * 4 + r, 64), 1e-30f);
#pragma unroll
    for (int t4 = 0; t4 < 4; ++t4)
#pragma unroll
      for (int r = 0; r < 4; ++r)
        oH[(hbase + qw + qt * 16 + quad * 4 + r) * 64 + t4 * 16 + r16] =
            f2bf(o[qt][t4][r] * rl[r]);
  }
}

// ======================= round-2 fallback (small ws) =======================
template<bool F32>
__device__ __forceinline__ bfrag load8(const void* base, size_t idx) {
  if constexpr (F32) {
    const float* p = (const float*)base + idx;
    float4 u = *reinterpret_cast<const float4*>(p);
    float4 v = *reinterpret_cast<const float4*>(p + 4);
    bfrag r;
    r[0]=(short)f2bf(u.x); r[1]=(short)f2bf(u.y); r[2]=(short)f2bf(u.z); r[3]=(short)f2bf(u.w);
    r[4]=(short)f2bf(v.x); r[5]=(short)f2bf(v.y); r[6]=(short)f2bf(v.z); r[7]=(short)f2bf(v.w);
    return r;
  } else {
    return *reinterpret_cast<const bfrag*>((const unsigned short*)base + idx);
  }
}

template<bool AF32, bool BF32>
__device__ __forceinline__ void gemm_body(const void* __restrict__ A, const void* __restrict__ Bt,
                                          void* __restrict__ C, int N, int K, bool outF32) {
  const int lane = threadIdx.x & 63, wave = threadIdx.x >> 6;
  const int r16 = lane & 15, quad = lane >> 4;
  const int m0 = (blockIdx.y * 4 + wave) * 16, n0 = blockIdx.x * 64;
  f32x4 acc[4];
#pragma unroll
  for (int i = 0; i < 4; ++i) acc[i] = (f32x4){0.f,0.f,0.f,0.f};
  const size_t aoff = (size_t)(m0 + r16) * K + quad * 8;
  const size_t boff = (size_t)(n0 + r16) * K + quad * 8;
  for (int k0 = 0; k0 < K; k0 += 32) {
    bfrag a = load8<AF32>(A, aoff + k0);
#pragma unroll
    for (int tt = 0; tt < 4; ++tt) {
      bfrag bb = load8<BF32>(Bt, boff + (size_t)tt * 16 * K + k0);
      acc[tt] = MFMA(a, bb, acc[tt]);
    }
  }
#pragma unroll
  for (int tt = 0; tt < 4; ++tt)
#pragma unroll
    for (int r = 0; r < 4; ++r) {
      const size_t ci = (size_t)(m0 + quad * 4 + r) * N + n0 + tt * 16 + r16;
      if (outF32) ((float*)C)[ci] = acc[tt][r];
      else        ((unsigned short*)C)[ci] = f2bf(acc[tt][r]);
    }
}

__global__ __launch_bounds__(256) void gemm_bt(const void* A, const void* Bt, void* C,
                                               int N, int K, const int* flags,
                                               int aFollows, int outFollows) {
  const int f = flags[0];
  const bool aF = (aFollows != 0) && (f != 0);
  const bool oF = (outFollows != 0) && (f != 0);
  if (f) { if (aF) gemm_body<true, true>(A, Bt, C, N, K, oF);
           else    gemm_body<false, true>(A, Bt, C, N, K, oF); }
  else     gemm_body<false, false>(A, Bt, C, N, K, oF);
}

__global__ __launch_bounds__(64) void fattn_r2(const unsigned short* __restrict__ xq,
                                               const unsigned short* __restrict__ xk,
                                               const unsigned short* __restrict__ xv,
                                               const void* __restrict__ mk,
                                               const int* __restrict__ flags,
                                               unsigned short* __restrict__ xo) {
  __shared__ unsigned short smemP[16 * 32];
  const int lane = threadIdx.x, r16 = lane & 15, quad = lane >> 4;
  const int q0 = blockIdx.x * 16, h = blockIdx.y, b = blockIdx.z;
  const int mmode = flags[1];
  const size_t base = (size_t)b * S_LEN * DIM + (size_t)h * HDIM;
  const size_t mbase = (size_t)b * S_LEN * S_LEN;
  bfrag aq0 = *reinterpret_cast<const bfrag*>(xq + base + (size_t)(q0 + r16) * DIM + quad * 8);
  bfrag aq1 = *reinterpret_cast<const bfrag*>(xq + base + (size_t)(q0 + r16) * DIM + 32 + quad * 8);
  f32x4 o[4];
#pragma unroll
  for (int i = 0; i < 4; ++i) o[i] = (f32x4){0.f,0.f,0.f,0.f};
  float m_r[4] = {-1e30f,-1e30f,-1e30f,-1e30f}, l_r[4] = {0.f,0.f,0.f,0.f};
  for (int kb = 0; kb < S_LEN; kb += 32) {
    const unsigned short* k0p = xk + base + (size_t)(kb + r16) * DIM + quad * 8;
    const unsigned short* k1p = k0p + (size_t)16 * DIM;
    f32x4 s0 = (f32x4){0.f,0.f,0.f,0.f}, s1 = (f32x4){0.f,0.f,0.f,0.f};
    s0 = MFMA(aq0, *reinterpret_cast<const bfrag*>(k0p), s0);
    s0 = MFMA(aq1, *reinterpret_cast<const bfrag*>(k0p + 32), s0);
    s1 = MFMA(aq0, *reinterpret_cast<const bfrag*>(k1p), s1);
    s1 = MFMA(aq1, *reinterpret_cast<const bfrag*>(k1p + 32), s1);
    float l0[4], l1[4], tmax[4];
#pragma unroll
    for (int r = 0; r < 4; ++r) {
      const size_t mrow = mbase + (size_t)(q0 + quad * 4 + r) * S_LEN + kb;
      l0[r] = mask_at(mk, mmode, mrow + r16) ? s0[r] * 0.125f : -1e30f;
      l1[r] = mask_at(mk, mmode, mrow + 16 + r16) ? s1[r] * 0.125f : -1e30f;
      tmax[r] = fmaxf(l0[r], l1[r]);
    }
#pragma unroll
    for (int off = 1; off < 16; off <<= 1)
#pragma unroll
      for (int r = 0; r < 4; ++r) tmax[r] = fmaxf(tmax[r], __shfl_xor(tmax[r], off, 64));
    float p0[4], p1[4], rsum[4];
#pragma unroll
    for (int r = 0; r < 4; ++r) {
      const float mnew = fmaxf(m_r[r], tmax[r]);
      const float alpha = __expf(m_r[r] - mnew);
      m_r[r] = mnew;
      p0[r] = (l0[r] <= -1e29f) ? 0.f : __expf(l0[r] - mnew);
      p1[r] = (l1[r] <= -1e29f) ? 0.f : __expf(l1[r] - mnew);
      rsum[r] = p0[r] + p1[r];
      l_r[r] *= alpha;
#pragma unroll
      for (int tt = 0; tt < 4; ++tt) o[tt][r] *= alpha;
    }
#pragma unroll
    for (int off = 1; off < 16; off <<= 1)
#pragma unroll
      for (int r = 0; r < 4; ++r) rsum[r] += __shfl_xor(rsum[r], off, 64);
#pragma unroll
    for (int r = 0; r < 4; ++r) l_r[r] += rsum[r];
#pragma unroll
    for (int r = 0; r < 4; ++r) {
      smemP[(quad * 4 + r) * 32 + r16] = f2bf(p0[r]);
      smemP[(quad * 4 + r) * 32 + 16 + r16] = f2bf(p1[r]);
    }
    __syncthreads();
    bfrag apf = *reinterpret_cast<const bfrag*>(&smemP[r16 * 32 + quad * 8]);
    const unsigned short* vbase = xv + base + (size_t)(kb + quad * 8) * DIM + r16;
#pragma unroll
    for (int tt = 0; tt < 4; ++tt) {
      bfrag bv;
#pragma unroll
      for (int j = 0; j < 8; ++j) bv[j] = (short)vbase[(size_t)j * DIM + tt * 16];
      o[tt] = MFMA(apf, bv, o[tt]);
    }
    __syncthreads();
  }
#pragma unroll
  for (int tt = 0; tt < 4; ++tt)
#pragma unroll
    for (int r = 0; r < 4; ++r)
      xo[base + (size_t)(q0 + quad * 4 + r) * DIM + tt * 16 + r16] = f2bf(o[tt][r] / l_r[r]);
}

extern "C" void kernel_launch(void* const* d_in, const int* in_sizes, int n_in,
                              void* d_out, int out_size, void* d_ws, size_t ws_size,
                              hipStream_t stream) {
  const void* x  = d_in[0];
  const void* mk = d_in[1];
  const void* wq = d_in[2];
  const void* wk = d_in[3];
  const void* wv = d_in[4];
  const void* wo = d_in[5];

  const size_t MiB = 1048576;
  const size_t NEED = 4096 + 90 * MiB;

  if (ws_size >= NEED) {
    char* p = (char*)d_ws;
    int* flags = (int*)p;                       p += 4096;
    unsigned short* xb  = (unsigned short*)p;   p += 16 * MiB;
    unsigned short* wqb = (unsigned short*)p;   p += 2 * MiB;   // wq/wk/wv contiguous
    unsigned short* wkb = (unsigned short*)p;   p += 2 * MiB;
    unsigned short* wvb = (unsigned short*)p;   p += 2 * MiB;
    unsigned short* wob = (unsigned short*)p;   p += 2 * MiB;
    unsigned long long* mb = (unsigned long long*)p; p += 2 * MiB;
    unsigned short* xqH = (unsigned short*)p;   p += 16 * MiB;  // xq/xk/xv contiguous
    unsigned short* xkH = (unsigned short*)p;   p += 16 * MiB;
    unsigned short* xvH = (unsigned short*)p;   p += 16 * MiB;  // reused as xoH
    unsigned short* xvT = (unsigned short*)p;   p += 16 * MiB;
    unsigned short* xoH = xvH;  // xvH dead after transposeV

    probe<<<1, 64, 0, stream>>>((const unsigned int*)x, (const unsigned int*)mk, flags);
    cvt<<<4096, 256, 0, stream>>>(x,  xb,  1048576, flags);
    cvt<<<512,  256, 0, stream>>>(wq, wqb, 131072, flags);
    cvt<<<512,  256, 0, stream>>>(wk, wkb, 131072, flags);
    cvt<<<512,  256, 0, stream>>>(wv, wvb, 131072, flags);
    cvt<<<512,  256, 0, stream>>>(wo, wob, 131072, flags);
    bitmask<<<65536, 256, 0, stream>>>(mk, flags, mb);

    // fused QKV projection: N = 3072 (wq/wk/wv rows contiguous)
    gemm128<<<dim3(24, 64), 256, 0, stream>>>(xb, wqb, xqH, flags, 0, 3);
    transposeV<<<dim3(32, 64), 256, 0, stream>>>(xvH, xvT);
    fattn<<<dim3(1024), 256, 0, stream>>>(xqH, xkH, xvT, mb, xoH);
    gemm128<<<dim3(8, 64), 256, 0, stream>>>(xoH, wob, d_out, flags, 1, 2);
  } else {
    // round-2 fallback
    int* flags = (int*)d_ws;
    unsigned short* xq = (unsigned short*)((char*)d_ws + 256);
    unsigned short* xk = xq + (size_t)8388608;
    unsigned short* xv = xk + (size_t)8388608;
    unsigned short* xo = xv + (size_t)8388608;
    probe<<<1, 64, 0, stream>>>((const unsigned int*)x, (const unsigned int*)mk, flags);
    dim3 gg(16, 128);
    gemm_bt<<<gg, 256, 0, stream>>>(x, wq, xq, 1024, 1024, flags, 1, 0);
    gemm_bt<<<gg, 256, 0, stream>>>(x, wk, xk, 1024, 1024, flags, 1, 0);
    gemm_bt<<<gg, 256, 0, stream>>>(x, wv, xv, 1024, 1024, flags, 1, 0);
    fattn_r2<<<dim3(128, NHEAD, 4), 64, 0, stream>>>(xq, xk, xv, mk, flags, xo);
    gemm_bt<<<gg, 256, 0, stream>>>(xo, wo, d_out, 1024, 1024, flags, 0, 1);
  }
}

// Round 8
// 431.108 us; speedup vs baseline: 4.4352x; 1.0656x over previous
//
#include <hip/hip_runtime.h>
#include <hip/hip_bf16.h>

#define S_LEN 2048
#define DIM   1024
#define NHEAD 16
#define HDIM  64
#define QSCALE 0.18033688f   // log2(e)/8, folded into Q at projection time

typedef __attribute__((ext_vector_type(8))) short bfrag;   // 8 bf16 = 4 VGPRs
typedef __attribute__((ext_vector_type(4))) float f32x4;   // MFMA C/D

#define MFMA(a,b,c) __builtin_amdgcn_mfma_f32_16x16x32_bf16((a),(b),(c),0,0,0)

__device__ __forceinline__ unsigned short f2bf(float x) {
  __hip_bfloat16 h = __float2bfloat16(x);
  return *reinterpret_cast<unsigned short*>(&h);
}

// packed 2xf32 -> 2xbf16 (v_cvt_pk_bf16_f32 on gfx950)
__device__ __forceinline__ unsigned int pk2bf(float a, float b) {
  float2 f2; f2.x = a; f2.y = b;
  __hip_bfloat162 b2 = __float22bfloat162_rn(f2);
  return *reinterpret_cast<unsigned int*>(&b2);
}

// async global->LDS, 16B per lane; LDS dest = wave-uniform base + lane*16
__device__ __forceinline__ void gll16(const unsigned short* g, unsigned short* l) {
  __builtin_amdgcn_global_load_lds(
      (const __attribute__((address_space(1))) unsigned int*)g,
      (__attribute__((address_space(3))) unsigned int*)l, 16, 0, 0);
}

// flags[0]: 0 = inputs bf16, 1 = inputs fp32
// flags[1]: mask mode 0=u8, 1=i32, 2=f32, 3=bf16
__global__ void probe(const unsigned int* __restrict__ x,
                      const unsigned int* __restrict__ mask,
                      int* __restrict__ flags) {
  const int lane = threadIdx.x;
  int insane = 0;
  for (int i = lane; i < 512; i += 64) {
    unsigned int w = x[i];
    unsigned int e = (w >> 7) & 0xFFu;
    bool sane = (e >= 90u && e <= 160u) || ((w & 0x7FFFu) == 0u);
    insane += sane ? 0 : 1;
  }
  bool all01 = true, allu8 = true, allf32 = true, allbf = true;
  for (int i = lane; i < 1024; i += 64) {
    unsigned int w = mask[i];
    all01  &= (w <= 1u);
    allu8  &= ((w & 0xFEFEFEFEu) == 0u);
    allf32 &= (w == 0u || w == 0x3F800000u);
    unsigned int lo = w & 0xFFFFu, hi = w >> 16;
    allbf  &= (lo == 0u || lo == 0x3F80u) && (hi == 0u || hi == 0x3F80u);
  }
#pragma unroll
  for (int off = 1; off < 64; off <<= 1) insane += __shfl_xor(insane, off, 64);
  const unsigned long long full = ~0ull;
  const bool g01  = __ballot(all01)  == full;
  const bool gu8  = __ballot(allu8)  == full;
  const bool gf32 = __ballot(allf32) == full;
  const bool gbf  = __ballot(allbf)  == full;
  if (lane == 0) {
    flags[0] = (insane > 128) ? 1 : 0;
    flags[1] = g01 ? 1 : (gu8 ? 0 : (gf32 ? 2 : (gbf ? 3 : 0)));
  }
}

__device__ __forceinline__ bool mask_at(const void* mk, int mode, size_t idx) {
  switch (mode) {
    case 0:  return ((const unsigned char*)mk)[idx]  != 0;
    case 1:  return ((const int*)mk)[idx]            != 0;
    case 2:  return ((const unsigned int*)mk)[idx]   != 0u;
    default: return ((const unsigned short*)mk)[idx] != 0;
  }
}

// One fused conversion kernel: x (4096 blocks) + 4 weights (512 blocks each).
__global__ __launch_bounds__(256) void cvt_all(
    const void* __restrict__ x,  const void* __restrict__ wq,
    const void* __restrict__ wk, const void* __restrict__ wv,
    const void* __restrict__ wo,
    unsigned short* __restrict__ xb,  unsigned short* __restrict__ wqb,
    unsigned short* __restrict__ wkb, unsigned short* __restrict__ wvb,
    unsigned short* __restrict__ wob, const int* __restrict__ flags) {
  const int bx = blockIdx.x;
  const void* src; unsigned short* dst; int i;
  if (bx < 4096) { src = x; dst = xb; i = bx * 256 + threadIdx.x; }
  else {
    const int r = (bx - 4096) >> 9, off = (bx - 4096) & 511;
    src = r == 0 ? wq : r == 1 ? wk : r == 2 ? wv : wo;
    dst = r == 0 ? wqb : r == 1 ? wkb : r == 2 ? wvb : wob;
    i = off * 256 + threadIdx.x;
  }
  if (flags[0]) {
    const float* p = (const float*)src + (size_t)i * 8;
    float4 a = *reinterpret_cast<const float4*>(p);
    float4 b = *reinterpret_cast<const float4*>(p + 4);
    unsigned int d0 = pk2bf(a.x, a.y), d1 = pk2bf(a.z, a.w);
    unsigned int d2 = pk2bf(b.x, b.y), d3 = pk2bf(b.z, b.w);
    uint4 o; o.x = d0; o.y = d1; o.z = d2; o.w = d3;
    *reinterpret_cast<uint4*>(dst + (size_t)i * 8) = o;
  } else {
    *reinterpret_cast<bfrag*>(dst + (size_t)i * 8) =
        reinterpret_cast<const bfrag*>(src)[i];
  }
}

// Bit-pack mask (any mode) -> u64 per 64 keys via ballot.
__global__ __launch_bounds__(256) void bitmask(const void* __restrict__ mk,
                                               const int* __restrict__ flags,
                                               unsigned long long* __restrict__ mb) {
  size_t gid = (size_t)blockIdx.x * 256 + threadIdx.x;
  bool v = mask_at(mk, flags[1], gid);
  unsigned long long w = __ballot(v);
  if ((threadIdx.x & 63) == 0) mb[gid >> 6] = w;
}

// ---------------- m97-style GEMM: C(8192xN) = A @ Bt^T, bf16, K=1024 ----------------
// cMode: 1 head-split bf16, 2 plain dtype-per-flag, 3 fused-QKV head-split
// (region 0 == Q gets pre-scaled by QSCALE).
__global__ __launch_bounds__(256) void gemm128(const unsigned short* __restrict__ A,
                                               const unsigned short* __restrict__ Bt,
                                               void* __restrict__ C,
                                               const int* __restrict__ flags,
                                               int aHsplit, int cMode) {
  __shared__ unsigned short As[128 * 32];
  __shared__ unsigned short Bs[128 * 32];
  const int t = threadIdx.x, lane = t & 63, wave = t >> 6;
  const int r16 = lane & 15, quad = lane >> 4;
  const int n0 = blockIdx.x * 128, m0 = blockIdx.y * 128;
  const int wm = (wave >> 1) * 64, wn = (wave & 1) * 64;
  const int arow = t >> 2, aseg = (t & 3) * 8;

  f32x4 acc[4][4];
#pragma unroll
  for (int i = 0; i < 4; ++i)
#pragma unroll
    for (int j = 0; j < 4; ++j) acc[i][j] = (f32x4){0.f, 0.f, 0.f, 0.f};

  for (int k0 = 0; k0 < 1024; k0 += 32) {
    __syncthreads();
#pragma unroll
    for (int rr = 0; rr < 2; ++rr) {
      const int m = m0 + rr * 64 + arow;
      const int k = k0 + aseg;
      const unsigned short* ga;
      if (aHsplit) ga = A + ((size_t)(((m >> 11) << 4) + (k >> 6)) * 2048 + (m & 2047)) * 64 + (k & 63);
      else         ga = A + (size_t)m * 1024 + k;
      gll16(ga, As + rr * 2048 + wave * 512);
      const unsigned short* gb = Bt + (size_t)(n0 + rr * 64 + arow) * 1024 + k0 + aseg;
      gll16(gb, Bs + rr * 2048 + wave * 512);
    }
    __syncthreads();

    bfrag af[4], bf[4];
#pragma unroll
    for (int i = 0; i < 4; ++i)
      af[i] = *reinterpret_cast<const bfrag*>(&As[(wm + i * 16 + r16) * 32 + quad * 8]);
#pragma unroll
    for (int j = 0; j < 4; ++j)
      bf[j] = *reinterpret_cast<const bfrag*>(&Bs[(wn + j * 16 + r16) * 32 + quad * 8]);
#pragma unroll
    for (int i = 0; i < 4; ++i)
#pragma unroll
      for (int j = 0; j < 4; ++j)
        acc[i][j] = MFMA(af[i], bf[j], acc[i][j]);
  }

  const int oF = (cMode == 2) ? flags[0] : 0;
#pragma unroll
  for (int i = 0; i < 4; ++i)
#pragma unroll
    for (int j = 0; j < 4; ++j)
#pragma unroll
      for (int r = 0; r < 4; ++r) {
        const int m = m0 + wm + i * 16 + quad * 4 + r;
        const int n = n0 + wn + j * 16 + r16;
        const float v = acc[i][j][r];
        if (cMode == 3) {
          const int region = n >> 10, nn = n & 1023;
          const float vv = (region == 0) ? v * QSCALE : v;
          const size_t idx = (size_t)region * 8388608 +
              ((size_t)((m >> 11) * NHEAD + (nn >> 6)) * 2048 + (m & 2047)) * 64 + (nn & 63);
          ((unsigned short*)C)[idx] = f2bf(vv);
        } else if (cMode == 1) {
          const size_t idx = ((size_t)((m >> 11) * NHEAD + (n >> 6)) * 2048 + (m & 2047)) * 64 + (n & 63);
          ((unsigned short*)C)[idx] = f2bf(v);
        } else {
          const size_t idx = (size_t)m * 1024 + n;
          if (oF) ((float*)C)[idx] = v;
          else    ((unsigned short*)C)[idx] = f2bf(v);
        }
      }
}

// xvH [bh][s][64] -> xvT [bh][64][s], 64x64 tiles through LDS.
__global__ __launch_bounds__(256) void transposeV(const unsigned short* __restrict__ xvH,
                                                  unsigned short* __restrict__ xvT) {
  __shared__ unsigned short Ts[64 * 80];
  const int t = threadIdx.x;
  const int s0 = blockIdx.x * 64, bh = blockIdx.y;
  const int sr = t >> 3, seg = (t & 7) * 8;
#pragma unroll
  for (int rr = 0; rr < 2; ++rr) {
    const int s = rr * 32 + sr;
    bfrag v = *reinterpret_cast<const bfrag*>(xvH + ((size_t)bh * 2048 + s0 + s) * 64 + seg);
#pragma unroll
    for (int j = 0; j < 8; ++j) Ts[(seg + j) * 80 + s] = (unsigned short)v[j];
  }
  __syncthreads();
#pragma unroll
  for (int rr = 0; rr < 2; ++rr) {
    const int d = rr * 32 + sr;
    bfrag o = *reinterpret_cast<const bfrag*>(&Ts[d * 80 + seg]);
    *reinterpret_cast<bfrag*>(xvT + ((size_t)bh * 64 + d) * 2048 + s0 + seg) = o;
  }
}

// ---------------- fattn v6 ----------------
// VALU-trimmed: Q pre-scaled at projection; packed bf16 converts; 1-shift mask
// extract; mask words prefetched at step top. XCD-local 1-D grid + K/V dbuf.
__global__ __launch_bounds__(256) void fattn(const unsigned short* __restrict__ qH,
                                             const unsigned short* __restrict__ kH,
                                             const unsigned short* __restrict__ vT,
                                             const unsigned long long* __restrict__ mb,
                                             unsigned short* __restrict__ oH) {
  __shared__ unsigned short Ks[2][64 * 64];
  __shared__ unsigned short Vs[2][64 * 64];
  __shared__ unsigned short Ps[4][16 * 72];
  const int t = threadIdx.x, lane = t & 63, wave = t >> 6;
  const int r16 = lane & 15, quad = lane >> 4;
  const int bid = blockIdx.x;
  const int bh = bid & 63, qidx = bid >> 6;
  const int b = bh >> 4;
  const int qw = qidx * 128 + wave * 32;
  const size_t hbase = (size_t)bh * S_LEN;

  bfrag aq[2][2];
#pragma unroll
  for (int qt = 0; qt < 2; ++qt)
#pragma unroll
    for (int hh = 0; hh < 2; ++hh)
      aq[qt][hh] = *reinterpret_cast<const bfrag*>(
          qH + (hbase + qw + qt * 16 + r16) * 64 + hh * 32 + quad * 8);

  f32x4 o[2][4];
#pragma unroll
  for (int qt = 0; qt < 2; ++qt)
#pragma unroll
    for (int i = 0; i < 4; ++i) o[qt][i] = (f32x4){0.f, 0.f, 0.f, 0.f};
  float lsum[2] = {0.f, 0.f};

  const int srow = lane >> 3;
  const int sg   = (lane & 7) ^ srow;

  auto stage = [&](int buf, int kb) {
#pragma unroll
    for (int rr = 0; rr < 2; ++rr) {
      const int row = rr * 32 + wave * 8 + srow;
      gll16(kH + (hbase + kb + row) * 64 + sg * 8, &Ks[buf][rr * 2048 + wave * 512]);
      gll16(vT + ((size_t)bh * 64 + row) * 2048 + kb + sg * 8, &Vs[buf][rr * 2048 + wave * 512]);
    }
  };

  stage(0, 0);
  int cur = 0;
  const unsigned long long* mrow = mb + ((size_t)b * S_LEN + qw + r16) * 32;

  for (int kb = 0; kb < S_LEN; kb += 64) {
    __syncthreads();
    if (kb + 64 < S_LEN) stage(cur ^ 1, kb + 64);

    // prefetch both mask words early (hide global latency behind ds/MFMA)
    unsigned long long w01[2];
    w01[0] = mrow[kb >> 6];
    w01[1] = mrow[16 * 32 + (kb >> 6)];

    bfrag kf[4][2], vf[4][2];
#pragma unroll
    for (int t4 = 0; t4 < 4; ++t4)
#pragma unroll
      for (int hh = 0; hh < 2; ++hh) {
        const int ch = (hh * 4 + quad) ^ (r16 & 7);
        kf[t4][hh] = *reinterpret_cast<const bfrag*>(&Ks[cur][(t4 * 16 + r16) * 64 + ch * 8]);
        vf[t4][hh] = *reinterpret_cast<const bfrag*>(&Vs[cur][(t4 * 16 + r16) * 64 + ch * 8]);
      }

#pragma unroll
    for (int qt = 0; qt < 2; ++qt) {
      f32x4 s[4];
#pragma unroll
      for (int t4 = 0; t4 < 4; ++t4) {
        f32x4 z = (f32x4){0.f, 0.f, 0.f, 0.f};
        z = MFMA(kf[t4][0], aq[qt][0], z);   // S^T[key][q], pre-scaled
        z = MFMA(kf[t4][1], aq[qt][1], z);
        s[t4] = z;
      }
      const unsigned long long ws = w01[qt] >> (quad * 4);
      const unsigned int wlo = (unsigned int)ws;
      const unsigned int whi = (unsigned int)(ws >> 32);

      float p[4][4];
#pragma unroll
      for (int t4 = 0; t4 < 4; ++t4) {
        const unsigned int word = (t4 < 2) ? wlo : whi;
        const int bpos = (t4 & 1) * 16;
#pragma unroll
        for (int r = 0; r < 4; ++r) {
          const float e = __builtin_amdgcn_exp2f(s[t4][r]);
          const float pv = (word & (1u << (bpos + r))) ? e : 0.f;
          p[t4][r] = pv;
          lsum[qt] += pv;
        }
      }
#pragma unroll
      for (int t4 = 0; t4 < 4; ++t4)
#pragma unroll
        for (int r = 0; r < 4; r += 2)
          *reinterpret_cast<unsigned int*>(
              &Ps[wave][r16 * 72 + t4 * 16 + quad * 4 + r]) = pk2bf(p[t4][r], p[t4][r + 1]);
      __asm__ volatile("s_waitcnt lgkmcnt(0)" ::: "memory");

      bfrag pa0 = *reinterpret_cast<const bfrag*>(&Ps[wave][r16 * 72 + quad * 8]);
      bfrag pa1 = *reinterpret_cast<const bfrag*>(&Ps[wave][r16 * 72 + 32 + quad * 8]);
#pragma unroll
      for (int t4 = 0; t4 < 4; ++t4) {
        o[qt][t4] = MFMA(pa0, vf[t4][0], o[qt][t4]);
        o[qt][t4] = MFMA(pa1, vf[t4][1], o[qt][t4]);
      }
    }
    cur ^= 1;
  }

#pragma unroll
  for (int qt = 0; qt < 2; ++qt) {
    float l = lsum[qt];
    l += __shfl_xor(l, 16, 64);
    l += __shfl_xor(l, 32, 64);
    float rl[4];
#pragma unroll
    for (int r = 0; r < 4; ++r)
      rl[r] = 1.f / fmaxf(__shfl(l, quad * 4 + r, 64), 1e-30f);
#pragma unroll
    for (int t4 = 0; t4 < 4; ++t4)
#pragma unroll
      for (int r = 0; r < 4; ++r)
        oH[(hbase + qw + qt * 16 + quad * 4 + r) * 64 + t4 * 16 + r16] =
            f2bf(o[qt][t4][r] * rl[r]);
  }
}

// ======================= round-2 fallback (small ws) =======================
template<bool F32>
__device__ __forceinline__ bfrag load8(const void* base, size_t idx) {
  if constexpr (F32) {
    const float* p = (const float*)base + idx;
    float4 u = *reinterpret_cast<const float4*>(p);
    float4 v = *reinterpret_cast<const float4*>(p + 4);
    bfrag r;
    r[0]=(short)f2bf(u.x); r[1]=(short)f2bf(u.y); r[2]=(short)f2bf(u.z); r[3]=(short)f2bf(u.w);
    r[4]=(short)f2bf(v.x); r[5]=(short)f2bf(v.y); r[6]=(short)f2bf(v.z); r[7]=(short)f2bf(v.w);
    return r;
  } else {
    return *reinterpret_cast<const bfrag*>((const unsigned short*)base + idx);
  }
}

template<bool AF32, bool BF32>
__device__ __forceinline__ void gemm_body(const void* __restrict__ A, const void* __restrict__ Bt,
                                          void* __restrict__ C, int N, int K, bool outF32) {
  const int lane = threadIdx.x & 63, wave = threadIdx.x >> 6;
  const int r16 = lane & 15, quad = lane >> 4;
  const int m0 = (blockIdx.y * 4 + wave) * 16, n0 = blockIdx.x * 64;
  f32x4 acc[4];
#pragma unroll
  for (int i = 0; i < 4; ++i) acc[i] = (f32x4){0.f,0.f,0.f,0.f};
  const size_t aoff = (size_t)(m0 + r16) * K + quad * 8;
  const size_t boff = (size_t)(n0 + r16) * K + quad * 8;
  for (int k0 = 0; k0 < K; k0 += 32) {
    bfrag a = load8<AF32>(A, aoff + k0);
#pragma unroll
    for (int tt = 0; tt < 4; ++tt) {
      bfrag bb = load8<BF32>(Bt, boff + (size_t)tt * 16 * K + k0);
      acc[tt] = MFMA(a, bb, acc[tt]);
    }
  }
#pragma unroll
  for (int tt = 0; tt < 4; ++tt)
#pragma unroll
    for (int r = 0; r < 4; ++r) {
      const size_t ci = (size_t)(m0 + quad * 4 + r) * N + n0 + tt * 16 + r16;
      if (outF32) ((float*)C)[ci] = acc[tt][r];
      else        ((unsigned short*)C)[ci] = f2bf(acc[tt][r]);
    }
}

__global__ __launch_bounds__(256) void gemm_bt(const void* A, const void* Bt, void* C,
                                               int N, int K, const int* flags,
                                               int aFollows, int outFollows) {
  const int f = flags[0];
  const bool aF = (aFollows != 0) && (f != 0);
  const bool oF = (outFollows != 0) && (f != 0);
  if (f) { if (aF) gemm_body<true, true>(A, Bt, C, N, K, oF);
           else    gemm_body<false, true>(A, Bt, C, N, K, oF); }
  else     gemm_body<false, false>(A, Bt, C, N, K, oF);
}

__global__ __launch_bounds__(64) void fattn_r2(const unsigned short* __restrict__ xq,
                                               const unsigned short* __restrict__ xk,
                                               const unsigned short* __restrict__ xv,
                                               const void* __restrict__ mk,
                                               const int* __restrict__ flags,
                                               unsigned short* __restrict__ xo) {
  __shared__ unsigned short smemP[16 * 32];
  const int lane = threadIdx.x, r16 = lane & 15, quad = lane >> 4;
  const int q0 = blockIdx.x * 16, h = blockIdx.y, b = blockIdx.z;
  const int mmode = flags[1];
  const size_t base = (size_t)b * S_LEN * DIM + (size_t)h * HDIM;
  const size_t mbase = (size_t)b * S_LEN * S_LEN;
  bfrag aq0 = *reinterpret_cast<const bfrag*>(xq + base + (size_t)(q0 + r16) * DIM + quad * 8);
  bfrag aq1 = *reinterpret_cast<const bfrag*>(xq + base + (size_t)(q0 + r16) * DIM + 32 + quad * 8);
  f32x4 o[4];
#pragma unroll
  for (int i = 0; i < 4; ++i) o[i] = (f32x4){0.f,0.f,0.f,0.f};
  float m_r[4] = {-1e30f,-1e30f,-1e30f,-1e30f}, l_r[4] = {0.f,0.f,0.f,0.f};
  for (int kb = 0; kb < S_LEN; kb += 32) {
    const unsigned short* k0p = xk + base + (size_t)(kb + r16) * DIM + quad * 8;
    const unsigned short* k1p = k0p + (size_t)16 * DIM;
    f32x4 s0 = (f32x4){0.f,0.f,0.f,0.f}, s1 = (f32x4){0.f,0.f,0.f,0.f};
    s0 = MFMA(aq0, *reinterpret_cast<const bfrag*>(k0p), s0);
    s0 = MFMA(aq1, *reinterpret_cast<const bfrag*>(k0p + 32), s0);
    s1 = MFMA(aq0, *reinterpret_cast<const bfrag*>(k1p), s1);
    s1 = MFMA(aq1, *reinterpret_cast<const bfrag*>(k1p + 32), s1);
    float l0[4], l1[4], tmax[4];
#pragma unroll
    for (int r = 0; r < 4; ++r) {
      const size_t mrow = mbase + (size_t)(q0 + quad * 4 + r) * S_LEN + kb;
      l0[r] = mask_at(mk, mmode, mrow + r16) ? s0[r] * 0.125f : -1e30f;
      l1[r] = mask_at(mk, mmode, mrow + 16 + r16) ? s1[r] * 0.125f : -1e30f;
      tmax[r] = fmaxf(l0[r], l1[r]);
    }
#pragma unroll
    for (int off = 1; off < 16; off <<= 1)
#pragma unroll
      for (int r = 0; r < 4; ++r) tmax[r] = fmaxf(tmax[r], __shfl_xor(tmax[r], off, 64));
    float p0[4], p1[4], rsum[4];
#pragma unroll
    for (int r = 0; r < 4; ++r) {
      const float mnew = fmaxf(m_r[r], tmax[r]);
      const float alpha = __expf(m_r[r] - mnew);
      m_r[r] = mnew;
      p0[r] = (l0[r] <= -1e29f) ? 0.f : __expf(l0[r] - mnew);
      p1[r] = (l1[r] <= -1e29f) ? 0.f : __expf(l1[r] - mnew);
      rsum[r] = p0[r] + p1[r];
      l_r[r] *= alpha;
#pragma unroll
      for (int tt = 0; tt < 4; ++tt) o[tt][r] *= alpha;
    }
#pragma unroll
    for (int off = 1; off < 16; off <<= 1)
#pragma unroll
      for (int r = 0; r < 4; ++r) rsum[r] += __shfl_xor(rsum[r], off, 64);
#pragma unroll
    for (int r = 0; r < 4; ++r) l_r[r] += rsum[r];
#pragma unroll
    for (int r = 0; r < 4; ++r) {
      smemP[(quad * 4 + r) * 32 + r16] = f2bf(p0[r]);
      smemP[(quad * 4 + r) * 32 + 16 + r16] = f2bf(p1[r]);
    }
    __syncthreads();
    bfrag apf = *reinterpret_cast<const bfrag*>(&smemP[r16 * 32 + quad * 8]);
    const unsigned short* vbase = xv + base + (size_t)(kb + quad * 8) * DIM + r16;
#pragma unroll
    for (int tt = 0; tt < 4; ++tt) {
      bfrag bv;
#pragma unroll
      for (int j = 0; j < 8; ++j) bv[j] = (short)vbase[(size_t)j * DIM + tt * 16];
      o[tt] = MFMA(apf, bv, o[tt]);
    }
    __syncthreads();
  }
#pragma unroll
  for (int tt = 0; tt < 4; ++tt)
#pragma unroll
    for (int r = 0; r < 4; ++r)
      xo[base + (size_t)(q0 + quad * 4 + r) * DIM + tt * 16 + r16] = f2bf(o[tt][r] / l_r[r]);
}

extern "C" void kernel_launch(void* const* d_in, const int* in_sizes, int n_in,
                              void* d_out, int out_size, void* d_ws, size_t ws_size,
                              hipStream_t stream) {
  const void* x  = d_in[0];
  const void* mk = d_in[1];
  const void* wq = d_in[2];
  const void* wk = d_in[3];
  const void* wv = d_in[4];
  const void* wo = d_in[5];

  const size_t MiB = 1048576;
  const size_t NEED = 4096 + 90 * MiB;

  if (ws_size >= NEED) {
    char* p = (char*)d_ws;
    int* flags = (int*)p;                       p += 4096;
    unsigned short* xb  = (unsigned short*)p;   p += 16 * MiB;
    unsigned short* wqb = (unsigned short*)p;   p += 2 * MiB;
    unsigned short* wkb = (unsigned short*)p;   p += 2 * MiB;
    unsigned short* wvb = (unsigned short*)p;   p += 2 * MiB;
    unsigned short* wob = (unsigned short*)p;   p += 2 * MiB;
    unsigned long long* mb = (unsigned long long*)p; p += 2 * MiB;
    unsigned short* xqH = (unsigned short*)p;   p += 16 * MiB;  // xq/xk/xv contiguous
    unsigned short* xkH = (unsigned short*)p;   p += 16 * MiB;
    unsigned short* xvH = (unsigned short*)p;   p += 16 * MiB;  // reused as xoH
    unsigned short* xvT = (unsigned short*)p;   p += 16 * MiB;
    unsigned short* xoH = xvH;  // xvH dead after transposeV

    probe<<<1, 64, 0, stream>>>((const unsigned int*)x, (const unsigned int*)mk, flags);
    cvt_all<<<6144, 256, 0, stream>>>(x, wq, wk, wv, wo, xb, wqb, wkb, wvb, wob, flags);
    bitmask<<<65536, 256, 0, stream>>>(mk, flags, mb);

    gemm128<<<dim3(24, 64), 256, 0, stream>>>(xb, wqb, xqH, flags, 0, 3);
    transposeV<<<dim3(32, 64), 256, 0, stream>>>(xvH, xvT);
    fattn<<<dim3(1024), 256, 0, stream>>>(xqH, xkH, xvT, mb, xoH);
    gemm128<<<dim3(8, 64), 256, 0, stream>>>(xoH, wob, d_out, flags, 1, 2);
  } else {
    // round-2 fallback
    int* flags = (int*)d_ws;
    unsigned short* xq = (unsigned short*)((char*)d_ws + 256);
    unsigned short* xk = xq + (size_t)8388608;
    unsigned short* xv = xk + (size_t)8388608;
    unsigned short* xo = xv + (size_t)8388608;
    probe<<<1, 64, 0, stream>>>((const unsigned int*)x, (const unsigned int*)mk, flags);
    dim3 gg(16, 128);
    gemm_bt<<<gg, 256, 0, stream>>>(x, wq, xq, 1024, 1024, flags, 1, 0);
    gemm_bt<<<gg, 256, 0, stream>>>(x, wk, xk, 1024, 1024, flags, 1, 0);
    gemm_bt<<<gg, 256, 0, stream>>>(x, wv, xv, 1024, 1024, flags, 1, 0);
    fattn_r2<<<dim3(128, NHEAD, 4), 64, 0, stream>>>(xq, xk, xv, mk, flags, xo);
    gemm_bt<<<gg, 256, 0, stream>>>(xo, wo, d_out, 1024, 1024, flags, 0, 1);
  }
}